// Round 3
// baseline (9047.064 us; speedup 1.0000x reference)
//
#include <hip/hip_runtime.h>
#include <hip/hip_cooperative_groups.h>
#include <float.h>
#include <math.h>

namespace cg = cooperative_groups;

// ============================================================================
// BeamSearchDecoder — MI355X. Greedy-equivalence: h0 = repeat(enc_h,K) and
// scores0 = 0 make all K=3 beams identical; top-3 of the 9 candidates = three
// copies of the argmax, so every beam takes the greedy token forever.
// decoded = one-hot(greedy seq), h = final greedy h x3, scores = cumulative
// (max - logsumexp) x3. All logits math fp32.
//
// R10 vs R9 (1905): R9 showed traffic is NOT the bottleneck (removing 65
// MB/step changed nothing). Step cost ~57 us vs ~18 us ideal => serial
// dispatch overhead (launch + ramp/drain bubbles of 66 small kernels on a
// serial chain). R10: ONE persistent cooperative kernel runs all 32 steps
// with grid.sync() between phases. 512 blocks x 256 thr = exactly 2
// blocks/CU (LDS 66 KB, launch_bounds(256,2)). Phase A: select+GRU on
// blocks 0..127 (R9 body). Phase B: fused gemv on blocks 0..499 (R9 body,
// LDS overlay). __threadfence() before each grid.sync() for cross-XCD
// visibility of pm/ps/pidx and the h ping-pong. Fallback to the R9
// multi-kernel path if cooperative launch is refused.
// ============================================================================

#define BB 32
#define HH 512
#define EE 256
#define VV 32000
#define TSTEPS 32
#define NCH 500                              // 64-col chunks (exact: 500*64)
#define PSTR 512                             // pm/ps/pidx row stride
#define DEC_ELEMS (BB * (TSTEPS + 1) * VV)   // 33,792,000
#define H_ELEMS (BB * 3 * HH)                // 49,152
#define SMEM_FLOATS 16512                    // 32*516 (gemv hs) >= gru needs

// ---------------------------------------------------------------------------
// Setup: tiled transpose W_out (V,H) -> Wt_out (H,V)
// ---------------------------------------------------------------------------
__global__ __launch_bounds__(256) void k_transpose_out(
    const float* __restrict__ W, float* __restrict__ Wt) {
  __shared__ float t[32][33];
  const int vb = blockIdx.x * 32;  // 1000
  const int kb = blockIdx.y * 32;  // 16
  const int c = threadIdx.x & 31, rq = threadIdx.x >> 5;
#pragma unroll
  for (int i = 0; i < 4; ++i) {
    int r = rq + i * 8;
    t[r][c] = W[(size_t)(vb + r) * HH + kb + c];
  }
  __syncthreads();
#pragma unroll
  for (int i = 0; i < 4; ++i) {
    int r = rq + i * 8;
    Wt[(size_t)(kb + r) * VV + vb + c] = t[c][r];
  }
}

// ---------------------------------------------------------------------------
// Setup: h0 = encoder_hidden, scores = 0, seq col 0 = START(=1)
// ---------------------------------------------------------------------------
__global__ __launch_bounds__(256) void k_init(
    const float* __restrict__ enc_h, float* __restrict__ hb0,
    float* __restrict__ scores, int* __restrict__ tok_seq) {
  int idx = blockIdx.x * 256 + threadIdx.x;  // 64*256
  if (idx < BB * HH) hb0[idx] = enc_h[idx];
  if (idx < BB) { scores[idx] = 0.0f; tok_seq[idx] = 1; }
}

// ---------------------------------------------------------------------------
// Fused full-K logits GEMV + per-chunk selection stats (R9 body).
// vb = 64-col chunk id (0..499). Thread: colq = tid&15 (4 cols via float4),
// rp = tid>>4 (rows 2rp, 2rp+1). Per 8-k group: 8 x b128 W loads + 64 FMA;
// depth-3 A/B/C pipeline. h (32 rows) in hs[32][516] via smem (pad ->
// conflict-free). Per-row max/argmax/sumexp via 16-lane shfl group.
// ---------------------------------------------------------------------------
#define FMA4(accv, hscal, wv)              \
  accv.x = fmaf(hscal, wv.x, accv.x);      \
  accv.y = fmaf(hscal, wv.y, accv.y);      \
  accv.z = fmaf(hscal, wv.z, accv.z);      \
  accv.w = fmaf(hscal, wv.w, accv.w);

#define LOADG(W, g)                                                    \
  {                                                                    \
    const float* p_ = wp + (size_t)(g) * 8 * VV;                       \
    _Pragma("unroll") for (int j_ = 0; j_ < 8; ++j_)                   \
        W[j_] = *(const float4*)(p_ + (size_t)j_ * VV);                \
  }

#define COMPG(W, g)                                                    \
  {                                                                    \
    const int k0_ = (g) * 8;                                           \
    _Pragma("unroll") for (int jj_ = 0; jj_ < 2; ++jj_) {              \
      const float4 h0_ = *(const float4*)&hs[r0][k0_ + jj_ * 4];       \
      const float4 h1_ = *(const float4*)&hs[r0 + 1][k0_ + jj_ * 4];   \
      FMA4(acc0, h0_.x, W[jj_ * 4 + 0]);                               \
      FMA4(acc0, h0_.y, W[jj_ * 4 + 1]);                               \
      FMA4(acc0, h0_.z, W[jj_ * 4 + 2]);                               \
      FMA4(acc0, h0_.w, W[jj_ * 4 + 3]);                               \
      FMA4(acc1, h1_.x, W[jj_ * 4 + 0]);                               \
      FMA4(acc1, h1_.y, W[jj_ * 4 + 1]);                               \
      FMA4(acc1, h1_.z, W[jj_ * 4 + 2]);                               \
      FMA4(acc1, h1_.w, W[jj_ * 4 + 3]);                               \
    }                                                                  \
  }

__device__ __forceinline__ void gemv_body(
    const int vb, const int tid, float* smem,
    const float* __restrict__ Wt, const float* __restrict__ hmat,
    const float* __restrict__ bout,
    float* __restrict__ pm, float* __restrict__ ps, int* __restrict__ pidx) {
  const int colq = tid & 15;
  const int rp = tid >> 4;
  const int r0 = rp * 2;
  const int col = vb * 64 + colq * 4;

  float (*hs)[516] = (float(*)[516])smem;  // 66 KB, padded
  {
    float4* hd = (float4*)smem;               // row r -> float4 offset r*129
    const float4* hp = (const float4*)hmat;   // row r -> float4 offset r*128
#pragma unroll
    for (int i = 0; i < 16; ++i) {
      const int idx = i * 256 + tid;
      const int r = idx >> 7, q = idx & 127;
      hd[r * 129 + q] = hp[idx];
    }
  }
  __syncthreads();

  const float* wp = Wt + col;
  float4 acc0 = {0.0f, 0.0f, 0.0f, 0.0f};
  float4 acc1 = {0.0f, 0.0f, 0.0f, 0.0f};

  float4 A[8], B[8], C[8];
  LOADG(A, 0);
  LOADG(B, 1);
#pragma unroll 1
  for (int g = 0; g < 63; g += 3) {   // 64 groups of 8 k
    LOADG(C, g + 2);
    COMPG(A, g);
    if (g + 3 < 64) LOADG(A, g + 3);
    COMPG(B, g + 1);
    if (g + 4 < 64) LOADG(B, g + 4);
    COMPG(C, g + 2);
  }
  COMPG(A, 63);

  {
    const float4 bo = *(const float4*)(bout + col);
    acc0.x += bo.x; acc0.y += bo.y; acc0.z += bo.z; acc0.w += bo.w;
    acc1.x += bo.x; acc1.y += bo.y; acc1.z += bo.z; acc1.w += bo.w;
  }

  // ---- per-row stats within the 16-lane col group (strict > : low idx) ----
  const int lane = tid & 63;

  float m0 = acc0.x; int i0 = col;
  if (acc0.y > m0) { m0 = acc0.y; i0 = col + 1; }
  if (acc0.z > m0) { m0 = acc0.z; i0 = col + 2; }
  if (acc0.w > m0) { m0 = acc0.w; i0 = col + 3; }
  float m1 = acc1.x; int i1 = col;
  if (acc1.y > m1) { m1 = acc1.y; i1 = col + 1; }
  if (acc1.z > m1) { m1 = acc1.z; i1 = col + 2; }
  if (acc1.w > m1) { m1 = acc1.w; i1 = col + 3; }
#pragma unroll
  for (int off = 1; off < 16; off <<= 1) {
    const float om0 = __shfl_xor(m0, off);
    const int oi0 = __shfl_xor(i0, off);
    if (om0 > m0 || (om0 == m0 && oi0 < i0)) { m0 = om0; i0 = oi0; }
    const float om1 = __shfl_xor(m1, off);
    const int oi1 = __shfl_xor(i1, off);
    if (om1 > m1 || (om1 == m1 && oi1 < i1)) { m1 = om1; i1 = oi1; }
  }
  float s0 = __expf(acc0.x - m0) + __expf(acc0.y - m0) +
             __expf(acc0.z - m0) + __expf(acc0.w - m0);
  float s1 = __expf(acc1.x - m1) + __expf(acc1.y - m1) +
             __expf(acc1.z - m1) + __expf(acc1.w - m1);
#pragma unroll
  for (int off = 1; off < 16; off <<= 1) {
    s0 += __shfl_xor(s0, off);
    s1 += __shfl_xor(s1, off);
  }

  if ((lane & 15) == 0) {
    pm[r0 * PSTR + vb] = m0;
    ps[r0 * PSTR + vb] = s0;
    pidx[r0 * PSTR + vb] = i0;
    pm[(r0 + 1) * PSTR + vb] = m1;
    ps[(r0 + 1) * PSTR + vb] = s1;
    pidx[(r0 + 1) * PSTR + vb] = i1;
  }
}

// ---------------------------------------------------------------------------
// GRU step with fused token-select prologue (R9 body). bid in 0..127:
// rg = bid>>4 (4 rows), jt = bid&15 (32 H-cols). step==TSTEPS: select only.
// Select reduces 500 chunk-partials: lane j holds chunks lane+64j (j=0..7).
// ---------------------------------------------------------------------------
__device__ __forceinline__ void gru_body(
    const int bid, const int tid, const int step, float* smem, int* toks,
    const float* __restrict__ emb,
    const float* __restrict__ W_ih,   // (1536, 256) native
    const float* __restrict__ W_hh,   // (1536, 512) native
    const float* __restrict__ b_ih, const float* __restrict__ b_hh,
    const float* __restrict__ hin, float* __restrict__ hout,
    const float* __restrict__ pm, const float* __restrict__ ps,
    const int* __restrict__ pidx,
    float* __restrict__ scores, int* __restrict__ tok_seq) {
  const int rg = bid >> 4;   // 0..7
  const int jt = bid & 15;   // 0..15
  const int r0 = rg * 4, j0 = jt * 32;
  const int lane = tid & 63, wv = tid >> 6;  // wv 0..3

  float (*xs)[EE] = (float(*)[EE])smem;                 // 4*256
  float (*hsm)[HH] = (float(*)[HH])(smem + 4 * EE);     // 4*512
  float* gpart = smem + 4 * EE + 4 * HH;                // 24*272 = 6528

  // ---- select: reduce 500 chunk-partials for row r0+wv ----
  if (step == 0) {
    if (tid < 4) toks[tid] = 1;  // START
  } else {
    const int row = r0 + wv;
    float mv[8], sv[8];
    int iv[8];
#pragma unroll
    for (int j = 0; j < 8; ++j) {
      const int ch = lane + 64 * j;
      const bool v = (ch < NCH);
      mv[j] = v ? pm[row * PSTR + ch] : -FLT_MAX;
      sv[j] = v ? ps[row * PSTR + ch] : 0.0f;
      iv[j] = v ? pidx[row * PSTR + ch] : 0x7fffffff;
    }
    float gm = mv[0];
    int gi = iv[0];
#pragma unroll
    for (int j = 1; j < 8; ++j)
      if (mv[j] > gm || (mv[j] == gm && iv[j] < gi)) { gm = mv[j]; gi = iv[j]; }
#pragma unroll
    for (int off = 1; off < 64; off <<= 1) {
      const float om = __shfl_xor(gm, off);
      const int oi = __shfl_xor(gi, off);
      if (om > gm || (om == gm && oi < gi)) { gm = om; gi = oi; }
    }
    float term = 0.0f;
#pragma unroll
    for (int j = 0; j < 8; ++j) term += sv[j] * __expf(mv[j] - gm);
#pragma unroll
    for (int off = 1; off < 64; off <<= 1) term += __shfl_xor(term, off);
    if (lane == 0) {
      toks[wv] = gi;
      if (jt == 0) {
        scores[row] -= logf(term);      // += max - logsumexp
        tok_seq[step * BB + row] = gi;  // seq column `step`
      }
    }
  }
  __syncthreads();
  if (step == TSTEPS) return;

  // ---- stage x = relu(emb[tok]) and h_prev ----
  for (int i = tid; i < 4 * EE; i += 256) {
    const int r = i >> 8, c = i & (EE - 1);
    const float e = emb[(size_t)toks[r] * EE + c];
    xs[r][c] = e > 0.0f ? e : 0.0f;
  }
  for (int i = tid; i < 4 * HH; i += 256) {
    const int r = i >> 9, c = i & (HH - 1);
    hsm[r][c] = hin[(r0 + r) * HH + c];
  }
  __syncthreads();

  const int jh = tid & 31, kq = tid >> 5;  // 32 cols x 8 k-slices
  const int j = j0 + jh;
  float ai[3][4], ah[3][4];
#pragma unroll
  for (int g = 0; g < 3; ++g)
#pragma unroll
    for (int r = 0; r < 4; ++r) { ai[g][r] = 0.0f; ah[g][r] = 0.0f; }

#pragma unroll 2
  for (int q = 0; q < 8; ++q) {
    const int k4 = kq * 32 + q * 4;
    float4 xr[4];
#pragma unroll
    for (int r = 0; r < 4; ++r) xr[r] = *(const float4*)&xs[r][k4];
#pragma unroll
    for (int g = 0; g < 3; ++g) {
      const float4 w = *(const float4*)&W_ih[(size_t)(g * HH + j) * EE + k4];
#pragma unroll
      for (int r = 0; r < 4; ++r) {
        ai[g][r] = fmaf(xr[r].x, w.x, ai[g][r]);
        ai[g][r] = fmaf(xr[r].y, w.y, ai[g][r]);
        ai[g][r] = fmaf(xr[r].z, w.z, ai[g][r]);
        ai[g][r] = fmaf(xr[r].w, w.w, ai[g][r]);
      }
    }
  }
#pragma unroll 2
  for (int q = 0; q < 16; ++q) {
    const int k4 = kq * 64 + q * 4;
    float4 hr[4];
#pragma unroll
    for (int r = 0; r < 4; ++r) hr[r] = *(const float4*)&hsm[r][k4];
#pragma unroll
    for (int g = 0; g < 3; ++g) {
      const float4 w = *(const float4*)&W_hh[(size_t)(g * HH + j) * HH + k4];
#pragma unroll
      for (int r = 0; r < 4; ++r) {
        ah[g][r] = fmaf(hr[r].x, w.x, ah[g][r]);
        ah[g][r] = fmaf(hr[r].y, w.y, ah[g][r]);
        ah[g][r] = fmaf(hr[r].z, w.z, ah[g][r]);
        ah[g][r] = fmaf(hr[r].w, w.w, ah[g][r]);
      }
    }
  }
  {
    const int base = kq * 34 + jh;
#pragma unroll
    for (int g = 0; g < 3; ++g)
#pragma unroll
      for (int r = 0; r < 4; ++r) {
        gpart[(g * 4 + r) * 272 + base] = ai[g][r];
        gpart[(12 + g * 4 + r) * 272 + base] = ah[g][r];
      }
  }
  __syncthreads();

  if (tid < 128) {
    const int r = tid >> 5, jh2 = tid & 31;
    const int j2 = j0 + jh2;
    float g6[6];
#pragma unroll
    for (int c = 0; c < 6; ++c) {
      const int cc = (c < 3) ? (c * 4 + r) : (12 + (c - 3) * 4 + r);
      float s = 0.0f;
#pragma unroll
      for (int q = 0; q < 8; ++q) s += gpart[cc * 272 + q * 34 + jh2];
      g6[c] = s;
    }
    const float ir = g6[0] + b_ih[j2];
    const float iz = g6[1] + b_ih[HH + j2];
    const float in_ = g6[2] + b_ih[2 * HH + j2];
    const float hr_ = g6[3] + b_hh[j2];
    const float hz = g6[4] + b_hh[HH + j2];
    const float hn = g6[5] + b_hh[2 * HH + j2];
    const float rr = 1.0f / (1.0f + expf(-(ir + hr_)));
    const float zz = 1.0f / (1.0f + expf(-(iz + hz)));
    const float nn = tanhf(in_ + rr * hn);
    hout[(r0 + r) * HH + j2] = (1.0f - zz) * nn + zz * hsm[r][j2];
  }
}

// ---------------------------------------------------------------------------
// Persistent cooperative kernel: all 32 steps + final select, grid.sync()
// between phases. 512 blocks = exactly 2/CU (LDS 66 KB, VGPR<=256 via
// launch_bounds(256,2)). Blocks 0..127: GRU phase; 0..499: GEMV phase; all
// blocks reach every grid.sync().
// ---------------------------------------------------------------------------
__global__ __launch_bounds__(256, 2) void k_persist(
    const float* __restrict__ Wt, const float* __restrict__ emb,
    const float* __restrict__ W_ih, const float* __restrict__ W_hh,
    const float* __restrict__ b_ih, const float* __restrict__ b_hh,
    const float* __restrict__ bout,
    float* hb0, float* hb1,
    float* pm, float* ps, int* pidx,
    float* scores, int* tok_seq) {
  cg::grid_group grid = cg::this_grid();
  __shared__ __align__(16) float smem[SMEM_FLOATS];
  __shared__ int toks[4];
  const int bid = blockIdx.x, tid = threadIdx.x;

  for (int t = 0; t <= TSTEPS; ++t) {
    float* hin = (t & 1) ? hb1 : hb0;
    float* hout = (t & 1) ? hb0 : hb1;
    // ---- phase A: select + GRU (select-only at t==TSTEPS) ----
    if (bid < 128)
      gru_body(bid, tid, t, smem, toks, emb, W_ih, W_hh, b_ih, b_hh,
               hin, hout, pm, ps, pidx, scores, tok_seq);
    __threadfence();   // writeback hout/tok_seq/scores; invalidate stale pm
    grid.sync();
    if (t == TSTEPS) break;
    // ---- phase B: fused logits GEMV + chunk stats ----
    if (bid < NCH)
      gemv_body(bid, tid, smem, Wt, hout, bout, pm, ps, pidx);
    __threadfence();   // writeback pm/ps/pidx; invalidate stale h
    grid.sync();
  }
}

// ---------------------------------------------------------------------------
// Fallback standalone kernels (R9 path) — same bodies.
// ---------------------------------------------------------------------------
__global__ __launch_bounds__(256) void k_gemv_fused(
    const float* __restrict__ Wt, const float* __restrict__ hmat,
    const float* __restrict__ bout,
    float* __restrict__ pm, float* __restrict__ ps, int* __restrict__ pidx) {
  __shared__ __align__(16) float smem[SMEM_FLOATS];
  gemv_body(blockIdx.x, threadIdx.x, smem, Wt, hmat, bout, pm, ps, pidx);
}

__global__ __launch_bounds__(256) void k_gru(
    const int step, const float* __restrict__ emb,
    const float* __restrict__ W_ih, const float* __restrict__ W_hh,
    const float* __restrict__ b_ih, const float* __restrict__ b_hh,
    const float* __restrict__ hin, float* __restrict__ hout,
    const float* __restrict__ pm, const float* __restrict__ ps,
    const int* __restrict__ pidx,
    float* __restrict__ scores, int* __restrict__ tok_seq) {
  __shared__ __align__(16) float smem[9600];
  __shared__ int toks[4];
  gru_body(blockIdx.x, threadIdx.x, step, smem, toks, emb, W_ih, W_hh,
           b_ih, b_hh, hin, hout, pm, ps, pidx, scores, tok_seq);
}

// ---------------------------------------------------------------------------
// Full-output writer: one-hot rows composed inline (no memset), h x3,
// scores x3. All stores float4, coalesced.
// ---------------------------------------------------------------------------
__global__ __launch_bounds__(256) void k_out(
    const int* __restrict__ tok_seq, const float* __restrict__ hfin,
    const float* __restrict__ scores, float* __restrict__ out) {
  const int blk = blockIdx.x, tid = threadIdx.x;
  if (blk < BB * (TSTEPS + 1)) {           // one (b,t) one-hot row
    const int b = blk / (TSTEPS + 1), t = blk % (TSTEPS + 1);
    const int tok = tok_seq[t * BB + b];
    const int tq = tok >> 2, tl = tok & 3;
    float4* op = (float4*)(out + (size_t)blk * VV);
    for (int i = tid; i < VV / 4; i += 256) {
      float4 z = {0.0f, 0.0f, 0.0f, 0.0f};
      if (i == tq) (&z.x)[tl] = 1.0f;
      op[i] = z;
    }
  } else if (blk < BB * (TSTEPS + 1) + 12) {  // h x3: 12288 float4
#pragma unroll
    for (int it = 0; it < 4; ++it) {
      const int idx = (blk - BB * (TSTEPS + 1)) * 1024 + it * 256 + tid;
      if (idx < H_ELEMS / 4) {
        const int fi = idx * 4;
        const int b = fi / (3 * HH);
        const int j0 = (fi % (3 * HH)) % HH;
        ((float4*)(out + DEC_ELEMS))[idx] =
            *(const float4*)(hfin + b * HH + j0);
      }
    }
  } else {                                   // scores x3: 96 floats
    if (tid < BB * 3) {
      out[(size_t)DEC_ELEMS + H_ELEMS + tid] = scores[tid / 3];
    }
  }
}

// ---------------------------------------------------------------------------
extern "C" void kernel_launch(void* const* d_in, const int* in_sizes, int n_in,
                              void* d_out, int out_size, void* d_ws, size_t ws_size,
                              hipStream_t stream) {
  const float* enc_h = (const float*)d_in[1];
  const float* emb   = (const float*)d_in[2];
  const float* W_ih  = (const float*)d_in[3];
  const float* W_hh  = (const float*)d_in[4];
  const float* b_ih  = (const float*)d_in[5];
  const float* b_hh  = (const float*)d_in[6];
  const float* W_out = (const float*)d_in[7];
  const float* b_out = (const float*)d_in[8];
  float* out = (float*)d_out;

  // workspace layout (floats) — ~65.9 MB total
  float* ws = (float*)d_ws;
  float* Wt_out  = ws;                       // 16,384,000
  float* hb0     = Wt_out + 16384000;        // 16,384
  float* hb1     = hb0 + BB * HH;            // 16,384
  float* pm      = hb1 + BB * HH;            // 32*512
  float* ps      = pm + BB * PSTR;           // 32*512
  float* scores  = ps + BB * PSTR;           // 32
  int*   pidx    = (int*)(scores + BB);      // 32*512
  int*   tok_seq = pidx + BB * PSTR;         // 33*32

  k_transpose_out<<<dim3(1000, 16), 256, 0, stream>>>(W_out, Wt_out);
  k_init<<<64, 256, 0, stream>>>(enc_h, hb0, scores, tok_seq);

  // ---- persistent cooperative path ----
  const float* Wt_c = Wt_out;
  void* args[] = {(void*)&Wt_c,  (void*)&emb,   (void*)&W_ih, (void*)&W_hh,
                  (void*)&b_ih,  (void*)&b_hh,  (void*)&b_out,
                  (void*)&hb0,   (void*)&hb1,
                  (void*)&pm,    (void*)&ps,    (void*)&pidx,
                  (void*)&scores, (void*)&tok_seq};
  hipError_t ce = hipLaunchCooperativeKernel(
      reinterpret_cast<const void*>(&k_persist), dim3(512), dim3(256),
      args, 0u, stream);

  if (ce != hipSuccess) {
    // ---- fallback: R9 multi-kernel path (identical bodies) ----
    for (int t = 0; t < TSTEPS; ++t) {
      float* hin  = (t & 1) ? hb1 : hb0;
      float* hout = (t & 1) ? hb0 : hb1;
      k_gru<<<128, 256, 0, stream>>>(t, emb, W_ih, W_hh, b_ih, b_hh,
                                     hin, hout, pm, ps, pidx, scores, tok_seq);
      k_gemv_fused<<<NCH, 256, 0, stream>>>(Wt_out, hout, b_out, pm, ps, pidx);
    }
    k_gru<<<128, 256, 0, stream>>>(TSTEPS, emb, W_ih, W_hh, b_ih, b_hh,
                                   hb0, hb1, pm, ps, pidx, scores, tok_seq);
  }

  // final h lives in hb0 (t=31 odd: hout=hb0); full-output writer
  k_out<<<BB * (TSTEPS + 1) + 13, 256, 0, stream>>>(tok_seq, hb0, scores, out);
}

// Round 4
// 2522.054 us; speedup vs baseline: 3.5872x; 3.5872x over previous
//
#include <hip/hip_runtime.h>
#include <float.h>
#include <math.h>

// ============================================================================
// BeamSearchDecoder — MI355X. Greedy-equivalence: h0 = repeat(enc_h,K) and
// scores0 = 0 make all K=3 beams identical; top-3 of the 9 candidates = three
// copies of the argmax, so every beam takes the greedy token forever.
// decoded = one-hot(greedy seq), h = final greedy h x3, scores = cumulative
// (max - logsumexp) x3. All logits math fp32.
//
// R11 vs R10 (9047, catastrophic): R10's grid.sync()+__threadfence() emitted
// device-scope cache maintenance (buffer_wbl2/inv) from every wave -> L2
// wiped 64x -> Wt refetched 27x (FETCH 1.78 GB @ 211 GB/s). R11 keeps the
// persistent kernel but synchronizes WITHOUT cache flushes:
//  - custom sense-reversing barrier from RELAXED agent-scope atomics
//    (cross-XCD coherent; no inv/wb emitted) + s_waitcnt vmcnt ordering
//    (__syncthreads already drains each wave's stores before arrival).
//  - cross-phase data (h, pm/ps/pidx) written with agent-scope relaxed
//    stores (sc1 write-through past writer L2), read with PLAIN cached
//    loads, made safe by single-write-then-read per address: h and stats
//    are PER-STEP buffers (hseq[34], pm/ps/pidx[32]) so no address is ever
//    cached stale. Read-only Wt/W_ih/W_hh/emb stay L2/LLC-warm all kernel.
//  - cooperative launch only for co-residency; grid.sync never called.
// Fallback: R9 multi-kernel path (same bodies) if coop launch refused.
// ============================================================================

#define BB 32
#define HH 512
#define EE 256
#define VV 32000
#define TSTEPS 32
#define NCH 500                              // 64-col chunks (exact: 500*64)
#define PSTR 512                             // pm/ps/pidx row stride
#define DEC_ELEMS (BB * (TSTEPS + 1) * VV)   // 33,792,000
#define H_ELEMS (BB * 3 * HH)                // 49,152
#define SMEM_FLOATS 16512                    // 32*516 (gemv hs) >= gru needs
#define HB (BB * HH)                         // 16384 floats per h buffer
#define SB (BB * PSTR)                       // 16384 per stats buffer

__device__ __forceinline__ void st_agent(float* p, float v) {
  __hip_atomic_store(p, v, __ATOMIC_RELAXED, __HIP_MEMORY_SCOPE_AGENT);
}
__device__ __forceinline__ void st_agent_i(int* p, int v) {
  __hip_atomic_store(p, v, __ATOMIC_RELAXED, __HIP_MEMORY_SCOPE_AGENT);
}

// ---------------------------------------------------------------------------
// Setup: tiled transpose W_out (V,H) -> Wt_out (H,V)
// ---------------------------------------------------------------------------
__global__ __launch_bounds__(256) void k_transpose_out(
    const float* __restrict__ W, float* __restrict__ Wt) {
  __shared__ float t[32][33];
  const int vb = blockIdx.x * 32;  // 1000
  const int kb = blockIdx.y * 32;  // 16
  const int c = threadIdx.x & 31, rq = threadIdx.x >> 5;
#pragma unroll
  for (int i = 0; i < 4; ++i) {
    int r = rq + i * 8;
    t[r][c] = W[(size_t)(vb + r) * HH + kb + c];
  }
  __syncthreads();
#pragma unroll
  for (int i = 0; i < 4; ++i) {
    int r = rq + i * 8;
    Wt[(size_t)(kb + r) * VV + vb + c] = t[c][r];
  }
}

// ---------------------------------------------------------------------------
// Setup: hseq[0] = encoder_hidden, scores = 0, seq col 0 = START(=1),
// barrier state zeroed.
// ---------------------------------------------------------------------------
__global__ __launch_bounds__(256) void k_init(
    const float* __restrict__ enc_h, float* __restrict__ h0,
    float* __restrict__ scores, int* __restrict__ tok_seq,
    unsigned* __restrict__ bar) {
  int idx = blockIdx.x * 256 + threadIdx.x;  // 64*256
  if (idx < BB * HH) h0[idx] = enc_h[idx];
  if (idx < BB) { scores[idx] = 0.0f; tok_seq[idx] = 1; }
  if (idx == 0) { bar[0] = 0u; bar[32] = 0u; }
}

// ---------------------------------------------------------------------------
// Flush-free grid barrier. bar[0]=count, bar[32]=generation (separate lines).
// Relaxed agent atomics only (no buffer_inv/wbl2). Ordering:
//  - entry __syncthreads drains every wave's VMEM (incl. sc1 stores) ->
//    all this block's cross-phase data globally visible before arrival.
//  - explicit vmcnt(0) between gen-read and count-add (prevents the add
//    becoming visible before we captured our generation), and between the
//    count-reset and gen-bump in the releasing block.
// ---------------------------------------------------------------------------
__device__ __forceinline__ void gbar(unsigned* bar, unsigned nblk) {
  __syncthreads();
  if (threadIdx.x == 0) {
    asm volatile("s_waitcnt vmcnt(0)" ::: "memory");
    unsigned g = __hip_atomic_load(&bar[32], __ATOMIC_RELAXED,
                                   __HIP_MEMORY_SCOPE_AGENT);
    asm volatile("s_waitcnt vmcnt(0)" ::: "memory");
    unsigned a = __hip_atomic_fetch_add(&bar[0], 1u, __ATOMIC_RELAXED,
                                        __HIP_MEMORY_SCOPE_AGENT);
    if (a == nblk - 1u) {
      __hip_atomic_store(&bar[0], 0u, __ATOMIC_RELAXED,
                         __HIP_MEMORY_SCOPE_AGENT);
      asm volatile("s_waitcnt vmcnt(0)" ::: "memory");
      __hip_atomic_fetch_add(&bar[32], 1u, __ATOMIC_RELAXED,
                             __HIP_MEMORY_SCOPE_AGENT);
    } else {
      while (__hip_atomic_load(&bar[32], __ATOMIC_RELAXED,
                               __HIP_MEMORY_SCOPE_AGENT) == g)
        __builtin_amdgcn_s_sleep(2);
    }
  }
  __syncthreads();
}

// ---------------------------------------------------------------------------
// Fused full-K logits GEMV + per-chunk selection stats (R9 body).
// vb = 64-col chunk id (0..499). Thread: colq = tid&15 (4 cols via float4),
// rp = tid>>4 (rows 2rp, 2rp+1). Per 8-k group: 8 x b128 W loads + 64 FMA;
// depth-3 A/B/C pipeline. h (32 rows) in hs[32][516] via smem. Stats written
// with agent-scope stores (write-through; readers use plain loads on
// never-before-touched per-step addresses).
// ---------------------------------------------------------------------------
#define FMA4(accv, hscal, wv)              \
  accv.x = fmaf(hscal, wv.x, accv.x);      \
  accv.y = fmaf(hscal, wv.y, accv.y);      \
  accv.z = fmaf(hscal, wv.z, accv.z);      \
  accv.w = fmaf(hscal, wv.w, accv.w);

#define LOADG(W, g)                                                    \
  {                                                                    \
    const float* p_ = wp + (size_t)(g) * 8 * VV;                       \
    _Pragma("unroll") for (int j_ = 0; j_ < 8; ++j_)                   \
        W[j_] = *(const float4*)(p_ + (size_t)j_ * VV);                \
  }

#define COMPG(W, g)                                                    \
  {                                                                    \
    const int k0_ = (g) * 8;                                           \
    _Pragma("unroll") for (int jj_ = 0; jj_ < 2; ++jj_) {              \
      const float4 h0_ = *(const float4*)&hs[r0][k0_ + jj_ * 4];       \
      const float4 h1_ = *(const float4*)&hs[r0 + 1][k0_ + jj_ * 4];   \
      FMA4(acc0, h0_.x, W[jj_ * 4 + 0]);                               \
      FMA4(acc0, h0_.y, W[jj_ * 4 + 1]);                               \
      FMA4(acc0, h0_.z, W[jj_ * 4 + 2]);                               \
      FMA4(acc0, h0_.w, W[jj_ * 4 + 3]);                               \
      FMA4(acc1, h1_.x, W[jj_ * 4 + 0]);                               \
      FMA4(acc1, h1_.y, W[jj_ * 4 + 1]);                               \
      FMA4(acc1, h1_.z, W[jj_ * 4 + 2]);                               \
      FMA4(acc1, h1_.w, W[jj_ * 4 + 3]);                               \
    }                                                                  \
  }

__device__ __forceinline__ void gemv_body(
    const int vb, const int tid, float* smem,
    const float* __restrict__ Wt, const float* __restrict__ hmat,
    const float* __restrict__ bout,
    float* __restrict__ pm, float* __restrict__ ps, int* __restrict__ pidx) {
  const int colq = tid & 15;
  const int rp = tid >> 4;
  const int r0 = rp * 2;
  const int col = vb * 64 + colq * 4;

  float (*hs)[516] = (float(*)[516])smem;  // 66 KB, padded
  {
    float4* hd = (float4*)smem;               // row r -> float4 offset r*129
    const float4* hp = (const float4*)hmat;   // row r -> float4 offset r*128
#pragma unroll
    for (int i = 0; i < 16; ++i) {
      const int idx = i * 256 + tid;
      const int r = idx >> 7, q = idx & 127;
      hd[r * 129 + q] = hp[idx];
    }
  }
  __syncthreads();

  const float* wp = Wt + col;
  float4 acc0 = {0.0f, 0.0f, 0.0f, 0.0f};
  float4 acc1 = {0.0f, 0.0f, 0.0f, 0.0f};

  float4 A[8], B[8], C[8];
  LOADG(A, 0);
  LOADG(B, 1);
#pragma unroll 1
  for (int g = 0; g < 63; g += 3) {   // 64 groups of 8 k
    LOADG(C, g + 2);
    COMPG(A, g);
    if (g + 3 < 64) LOADG(A, g + 3);
    COMPG(B, g + 1);
    if (g + 4 < 64) LOADG(B, g + 4);
    COMPG(C, g + 2);
  }
  COMPG(A, 63);

  {
    const float4 bo = *(const float4*)(bout + col);
    acc0.x += bo.x; acc0.y += bo.y; acc0.z += bo.z; acc0.w += bo.w;
    acc1.x += bo.x; acc1.y += bo.y; acc1.z += bo.z; acc1.w += bo.w;
  }

  // ---- per-row stats within the 16-lane col group (strict > : low idx) ----
  const int lane = tid & 63;

  float m0 = acc0.x; int i0 = col;
  if (acc0.y > m0) { m0 = acc0.y; i0 = col + 1; }
  if (acc0.z > m0) { m0 = acc0.z; i0 = col + 2; }
  if (acc0.w > m0) { m0 = acc0.w; i0 = col + 3; }
  float m1 = acc1.x; int i1 = col;
  if (acc1.y > m1) { m1 = acc1.y; i1 = col + 1; }
  if (acc1.z > m1) { m1 = acc1.z; i1 = col + 2; }
  if (acc1.w > m1) { m1 = acc1.w; i1 = col + 3; }
#pragma unroll
  for (int off = 1; off < 16; off <<= 1) {
    const float om0 = __shfl_xor(m0, off);
    const int oi0 = __shfl_xor(i0, off);
    if (om0 > m0 || (om0 == m0 && oi0 < i0)) { m0 = om0; i0 = oi0; }
    const float om1 = __shfl_xor(m1, off);
    const int oi1 = __shfl_xor(i1, off);
    if (om1 > m1 || (om1 == m1 && oi1 < i1)) { m1 = om1; i1 = oi1; }
  }
  float s0 = __expf(acc0.x - m0) + __expf(acc0.y - m0) +
             __expf(acc0.z - m0) + __expf(acc0.w - m0);
  float s1 = __expf(acc1.x - m1) + __expf(acc1.y - m1) +
             __expf(acc1.z - m1) + __expf(acc1.w - m1);
#pragma unroll
  for (int off = 1; off < 16; off <<= 1) {
    s0 += __shfl_xor(s0, off);
    s1 += __shfl_xor(s1, off);
  }

  if ((lane & 15) == 0) {
    st_agent(&pm[r0 * PSTR + vb], m0);
    st_agent(&ps[r0 * PSTR + vb], s0);
    st_agent_i(&pidx[r0 * PSTR + vb], i0);
    st_agent(&pm[(r0 + 1) * PSTR + vb], m1);
    st_agent(&ps[(r0 + 1) * PSTR + vb], s1);
    st_agent_i(&pidx[(r0 + 1) * PSTR + vb], i1);
  }
}

// ---------------------------------------------------------------------------
// GRU step with fused token-select prologue (R9 body). bid in 0..127:
// rg = bid>>4 (4 rows), jt = bid&15 (32 H-cols). step==TSTEPS: select only.
// Select reads PREVIOUS step's stats (plain loads, per-step buffers).
// hout written with agent-scope stores.
// ---------------------------------------------------------------------------
__device__ __forceinline__ void gru_body(
    const int bid, const int tid, const int step, float* smem, int* toks,
    const float* __restrict__ emb,
    const float* __restrict__ W_ih,   // (1536, 256) native
    const float* __restrict__ W_hh,   // (1536, 512) native
    const float* __restrict__ b_ih, const float* __restrict__ b_hh,
    const float* __restrict__ hin, float* __restrict__ hout,
    const float* __restrict__ pmt, const float* __restrict__ pst,
    const int* __restrict__ pidxt,
    float* __restrict__ scores, int* __restrict__ tok_seq) {
  const int rg = bid >> 4;   // 0..7
  const int jt = bid & 15;   // 0..15
  const int r0 = rg * 4, j0 = jt * 32;
  const int lane = tid & 63, wv = tid >> 6;  // wv 0..3

  float (*xs)[EE] = (float(*)[EE])smem;                 // 4*256
  float (*hsm)[HH] = (float(*)[HH])(smem + 4 * EE);     // 4*512
  float* gpart = smem + 4 * EE + 4 * HH;                // 24*272 = 6528

  // ---- select: reduce 500 chunk-partials for row r0+wv ----
  if (step == 0) {
    if (tid < 4) toks[tid] = 1;  // START
  } else {
    const int row = r0 + wv;
    float mv[8], sv[8];
    int iv[8];
#pragma unroll
    for (int j = 0; j < 8; ++j) {
      const int ch = lane + 64 * j;
      const bool v = (ch < NCH);
      mv[j] = v ? pmt[row * PSTR + ch] : -FLT_MAX;
      sv[j] = v ? pst[row * PSTR + ch] : 0.0f;
      iv[j] = v ? pidxt[row * PSTR + ch] : 0x7fffffff;
    }
    float gm = mv[0];
    int gi = iv[0];
#pragma unroll
    for (int j = 1; j < 8; ++j)
      if (mv[j] > gm || (mv[j] == gm && iv[j] < gi)) { gm = mv[j]; gi = iv[j]; }
#pragma unroll
    for (int off = 1; off < 64; off <<= 1) {
      const float om = __shfl_xor(gm, off);
      const int oi = __shfl_xor(gi, off);
      if (om > gm || (om == gm && oi < gi)) { gm = om; gi = oi; }
    }
    float term = 0.0f;
#pragma unroll
    for (int j = 0; j < 8; ++j) term += sv[j] * __expf(mv[j] - gm);
#pragma unroll
    for (int off = 1; off < 64; off <<= 1) term += __shfl_xor(term, off);
    if (lane == 0) {
      toks[wv] = gi;
      if (jt == 0) {
        scores[row] -= logf(term);      // += max - logsumexp
        tok_seq[step * BB + row] = gi;  // seq column `step`
      }
    }
  }
  __syncthreads();
  if (step == TSTEPS) return;

  // ---- stage x = relu(emb[tok]) and h_prev ----
  for (int i = tid; i < 4 * EE; i += 256) {
    const int r = i >> 8, c = i & (EE - 1);
    const float e = emb[(size_t)toks[r] * EE + c];
    xs[r][c] = e > 0.0f ? e : 0.0f;
  }
  for (int i = tid; i < 4 * HH; i += 256) {
    const int r = i >> 9, c = i & (HH - 1);
    hsm[r][c] = hin[(r0 + r) * HH + c];
  }
  __syncthreads();

  const int jh = tid & 31, kq = tid >> 5;  // 32 cols x 8 k-slices
  const int j = j0 + jh;
  float ai[3][4], ah[3][4];
#pragma unroll
  for (int g = 0; g < 3; ++g)
#pragma unroll
    for (int r = 0; r < 4; ++r) { ai[g][r] = 0.0f; ah[g][r] = 0.0f; }

#pragma unroll 2
  for (int q = 0; q < 8; ++q) {
    const int k4 = kq * 32 + q * 4;
    float4 xr[4];
#pragma unroll
    for (int r = 0; r < 4; ++r) xr[r] = *(const float4*)&xs[r][k4];
#pragma unroll
    for (int g = 0; g < 3; ++g) {
      const float4 w = *(const float4*)&W_ih[(size_t)(g * HH + j) * EE + k4];
#pragma unroll
      for (int r = 0; r < 4; ++r) {
        ai[g][r] = fmaf(xr[r].x, w.x, ai[g][r]);
        ai[g][r] = fmaf(xr[r].y, w.y, ai[g][r]);
        ai[g][r] = fmaf(xr[r].z, w.z, ai[g][r]);
        ai[g][r] = fmaf(xr[r].w, w.w, ai[g][r]);
      }
    }
  }
#pragma unroll 2
  for (int q = 0; q < 16; ++q) {
    const int k4 = kq * 64 + q * 4;
    float4 hr[4];
#pragma unroll
    for (int r = 0; r < 4; ++r) hr[r] = *(const float4*)&hsm[r][k4];
#pragma unroll
    for (int g = 0; g < 3; ++g) {
      const float4 w = *(const float4*)&W_hh[(size_t)(g * HH + j) * HH + k4];
#pragma unroll
      for (int r = 0; r < 4; ++r) {
        ah[g][r] = fmaf(hr[r].x, w.x, ah[g][r]);
        ah[g][r] = fmaf(hr[r].y, w.y, ah[g][r]);
        ah[g][r] = fmaf(hr[r].z, w.z, ah[g][r]);
        ah[g][r] = fmaf(hr[r].w, w.w, ah[g][r]);
      }
    }
  }
  {
    const int base = kq * 34 + jh;
#pragma unroll
    for (int g = 0; g < 3; ++g)
#pragma unroll
      for (int r = 0; r < 4; ++r) {
        gpart[(g * 4 + r) * 272 + base] = ai[g][r];
        gpart[(12 + g * 4 + r) * 272 + base] = ah[g][r];
      }
  }
  __syncthreads();

  if (tid < 128) {
    const int r = tid >> 5, jh2 = tid & 31;
    const int j2 = j0 + jh2;
    float g6[6];
#pragma unroll
    for (int c = 0; c < 6; ++c) {
      const int cc = (c < 3) ? (c * 4 + r) : (12 + (c - 3) * 4 + r);
      float s = 0.0f;
#pragma unroll
      for (int q = 0; q < 8; ++q) s += gpart[cc * 272 + q * 34 + jh2];
      g6[c] = s;
    }
    const float ir = g6[0] + b_ih[j2];
    const float iz = g6[1] + b_ih[HH + j2];
    const float in_ = g6[2] + b_ih[2 * HH + j2];
    const float hr_ = g6[3] + b_hh[j2];
    const float hz = g6[4] + b_hh[HH + j2];
    const float hn = g6[5] + b_hh[2 * HH + j2];
    const float rr = 1.0f / (1.0f + expf(-(ir + hr_)));
    const float zz = 1.0f / (1.0f + expf(-(iz + hz)));
    const float nn = tanhf(in_ + rr * hn);
    st_agent(&hout[(r0 + r) * HH + j2], (1.0f - zz) * nn + zz * hsm[r][j2]);
  }
}

// ---------------------------------------------------------------------------
// Persistent kernel: all 32 steps + final select; flush-free gbar between
// phases. 512 blocks = exactly 2/CU (LDS 66 KB, launch_bounds(256,2)).
// Launched cooperatively ONLY for the co-residency guarantee.
// ---------------------------------------------------------------------------
__global__ __launch_bounds__(256, 2) void k_persist(
    const float* __restrict__ Wt, const float* __restrict__ emb,
    const float* __restrict__ W_ih, const float* __restrict__ W_hh,
    const float* __restrict__ b_ih, const float* __restrict__ b_hh,
    const float* __restrict__ bout,
    float* hseq, float* pmT, float* psT, int* pidxT,
    float* scores, int* tok_seq, unsigned* bar) {
  __shared__ __align__(16) float smem[SMEM_FLOATS];
  __shared__ int toks[4];
  const int bid = blockIdx.x, tid = threadIdx.x;

  for (int t = 0; t <= TSTEPS; ++t) {
    const float* hin = hseq + (size_t)t * HB;
    float* hout = hseq + (size_t)(t + 1) * HB;   // t==TSTEPS: never written
    const int tp = (t > 0) ? (t - 1) : 0;
    // ---- phase A: select + GRU (select-only at t==TSTEPS) ----
    if (bid < 128)
      gru_body(bid, tid, t, smem, toks, emb, W_ih, W_hh, b_ih, b_hh,
               hin, hout, pmT + (size_t)tp * SB, psT + (size_t)tp * SB,
               pidxT + (size_t)tp * SB, scores, tok_seq);
    gbar(bar, 512u);
    if (t == TSTEPS) break;
    // ---- phase B: fused logits GEMV + chunk stats (per-step buffers) ----
    if (bid < NCH)
      gemv_body(bid, tid, smem, Wt, hout, bout,
                pmT + (size_t)t * SB, psT + (size_t)t * SB,
                pidxT + (size_t)t * SB);
    gbar(bar, 512u);
  }
}

// ---------------------------------------------------------------------------
// Fallback standalone kernels (R9 path) — same bodies, per-step buffers.
// ---------------------------------------------------------------------------
__global__ __launch_bounds__(256) void k_gemv_fused(
    const float* __restrict__ Wt, const float* __restrict__ hmat,
    const float* __restrict__ bout,
    float* __restrict__ pm, float* __restrict__ ps, int* __restrict__ pidx) {
  __shared__ __align__(16) float smem[SMEM_FLOATS];
  gemv_body(blockIdx.x, threadIdx.x, smem, Wt, hmat, bout, pm, ps, pidx);
}

__global__ __launch_bounds__(256) void k_gru(
    const int step, const float* __restrict__ emb,
    const float* __restrict__ W_ih, const float* __restrict__ W_hh,
    const float* __restrict__ b_ih, const float* __restrict__ b_hh,
    const float* __restrict__ hin, float* __restrict__ hout,
    const float* __restrict__ pmt, const float* __restrict__ pst,
    const int* __restrict__ pidxt,
    float* __restrict__ scores, int* __restrict__ tok_seq) {
  __shared__ __align__(16) float smem[9600];
  __shared__ int toks[4];
  gru_body(blockIdx.x, threadIdx.x, step, smem, toks, emb, W_ih, W_hh,
           b_ih, b_hh, hin, hout, pmt, pst, pidxt, scores, tok_seq);
}

// ---------------------------------------------------------------------------
// Full-output writer: one-hot rows composed inline (no memset), h x3,
// scores x3. All stores float4, coalesced.
// ---------------------------------------------------------------------------
__global__ __launch_bounds__(256) void k_out(
    const int* __restrict__ tok_seq, const float* __restrict__ hfin,
    const float* __restrict__ scores, float* __restrict__ out) {
  const int blk = blockIdx.x, tid = threadIdx.x;
  if (blk < BB * (TSTEPS + 1)) {           // one (b,t) one-hot row
    const int b = blk / (TSTEPS + 1), t = blk % (TSTEPS + 1);
    const int tok = tok_seq[t * BB + b];
    const int tq = tok >> 2, tl = tok & 3;
    float4* op = (float4*)(out + (size_t)blk * VV);
    for (int i = tid; i < VV / 4; i += 256) {
      float4 z = {0.0f, 0.0f, 0.0f, 0.0f};
      if (i == tq) (&z.x)[tl] = 1.0f;
      op[i] = z;
    }
  } else if (blk < BB * (TSTEPS + 1) + 12) {  // h x3: 12288 float4
#pragma unroll
    for (int it = 0; it < 4; ++it) {
      const int idx = (blk - BB * (TSTEPS + 1)) * 1024 + it * 256 + tid;
      if (idx < H_ELEMS / 4) {
        const int fi = idx * 4;
        const int b = fi / (3 * HH);
        const int j0 = (fi % (3 * HH)) % HH;
        ((float4*)(out + DEC_ELEMS))[idx] =
            *(const float4*)(hfin + b * HH + j0);
      }
    }
  } else {                                   // scores x3: 96 floats
    if (tid < BB * 3) {
      out[(size_t)DEC_ELEMS + H_ELEMS + tid] = scores[tid / 3];
    }
  }
}

// ---------------------------------------------------------------------------
extern "C" void kernel_launch(void* const* d_in, const int* in_sizes, int n_in,
                              void* d_out, int out_size, void* d_ws, size_t ws_size,
                              hipStream_t stream) {
  const float* enc_h = (const float*)d_in[1];
  const float* emb   = (const float*)d_in[2];
  const float* W_ih  = (const float*)d_in[3];
  const float* W_hh  = (const float*)d_in[4];
  const float* b_ih  = (const float*)d_in[5];
  const float* b_hh  = (const float*)d_in[6];
  const float* W_out = (const float*)d_in[7];
  const float* b_out = (const float*)d_in[8];
  float* out = (float*)d_out;

  // workspace layout (floats) — ~74 MB total
  float* ws = (float*)d_ws;
  float* Wt_out  = ws;                        // 16,384,000
  float* hseq    = Wt_out + 16384000;         // 34 * 16384 (h after t steps)
  float* pmT     = hseq + 34 * HB;            // 32 * 16384 (per-step stats)
  float* psT     = pmT + 32 * SB;             // 32 * 16384
  float* scores  = psT + 32 * SB;             // 32
  int*   pidxT   = (int*)(scores + BB);       // 32 * 16384
  int*   tok_seq = pidxT + 32 * SB;           // 33*32
  unsigned* bar  = (unsigned*)(tok_seq + BB * (TSTEPS + 1));  // 64

  k_transpose_out<<<dim3(1000, 16), 256, 0, stream>>>(W_out, Wt_out);
  k_init<<<64, 256, 0, stream>>>(enc_h, hseq, scores, tok_seq, bar);

  // ---- persistent flush-free path (cooperative launch for co-residency) ----
  const float* Wt_c = Wt_out;
  void* args[] = {(void*)&Wt_c,  (void*)&emb,  (void*)&W_ih, (void*)&W_hh,
                  (void*)&b_ih,  (void*)&b_hh, (void*)&b_out,
                  (void*)&hseq,  (void*)&pmT,  (void*)&psT,  (void*)&pidxT,
                  (void*)&scores, (void*)&tok_seq, (void*)&bar};
  hipError_t ce = hipLaunchCooperativeKernel(
      reinterpret_cast<const void*>(&k_persist), dim3(512), dim3(256),
      args, 0u, stream);

  if (ce != hipSuccess) {
    // ---- fallback: multi-kernel path (identical bodies) ----
    for (int t = 0; t < TSTEPS; ++t) {
      const int tp = (t > 0) ? (t - 1) : 0;
      k_gru<<<128, 256, 0, stream>>>(
          t, emb, W_ih, W_hh, b_ih, b_hh,
          hseq + (size_t)t * HB, hseq + (size_t)(t + 1) * HB,
          pmT + (size_t)tp * SB, psT + (size_t)tp * SB,
          pidxT + (size_t)tp * SB, scores, tok_seq);
      k_gemv_fused<<<NCH, 256, 0, stream>>>(
          Wt_out, hseq + (size_t)(t + 1) * HB, b_out,
          pmT + (size_t)t * SB, psT + (size_t)t * SB,
          pidxT + (size_t)t * SB);
    }
    k_gru<<<128, 256, 0, stream>>>(
        TSTEPS, emb, W_ih, W_hh, b_ih, b_hh,
        hseq + (size_t)TSTEPS * HB, hseq + (size_t)(TSTEPS + 1) * HB,
        pmT + (size_t)(TSTEPS - 1) * SB, psT + (size_t)(TSTEPS - 1) * SB,
        pidxT + (size_t)(TSTEPS - 1) * SB, scores, tok_seq);
  }

  // final h = hseq[32]; full-output writer
  k_out<<<BB * (TSTEPS + 1) + 13, 256, 0, stream>>>(
      tok_seq, hseq + (size_t)TSTEPS * HB, scores, out);
}

// Round 5
// 1779.203 us; speedup vs baseline: 5.0849x; 1.4175x over previous
//
#include <hip/hip_runtime.h>
#include <float.h>
#include <math.h>

// ============================================================================
// BeamSearchDecoder — MI355X. Greedy-equivalence: h0 = repeat(enc_h,K) and
// scores0 = 0 make all K=3 beams identical; top-3 of the 9 candidates = three
// copies of the argmax, so every beam takes the greedy token forever.
// decoded = one-hot(greedy seq), h = final greedy h x3, scores = cumulative
// (max - logsumexp) x3. All logits math fp32.
//
// R12 vs R11 (2522; k_persist 2405, FETCH 1.70 GB = 26x Wt): Wt (65.5 MB)
// can NEVER be L2-resident (32 MB aggregate) -> every step re-pulled it over
// the fabric (~45 us/step, the session-long wall). R12 pins Wt in REGISTERS:
// 512 blocks x 256 thr x 128 VGPR (float2 wreg[64], static indices) = 64 MB
// of register-resident weights, loaded once in the prologue. Per-step gemv
// becomes pure VALU (4096 FMA/thread, ~7 us floor) + LDS-broadcast h +
// in-wave shfl_xor(32) k-merge + 8 KB LDS 4-way reduce + per-chunk stats.
// Persistent flush-free barrier (R11-proven) unchanged; GRU phase (proven
// body) unchanged on blocks 0..127. Per-step traffic: h/x/stats/gru-W only.
// Fallback: R9 multi-kernel path (global-load gemv) if coop launch refused.
// ============================================================================

#define BB 32
#define HH 512
#define EE 256
#define VV 32000
#define TSTEPS 32
#define NCH 500                              // 64-col chunks (exact: 500*64)
#define PSTR 512                             // pm/ps/pidx row stride
#define DEC_ELEMS (BB * (TSTEPS + 1) * VV)   // 33,792,000
#define H_ELEMS (BB * 3 * HH)                // 49,152
#define SMEM_FLOATS 18432                    // hs 32*512 + part 4*8*64
#define HB (BB * HH)                         // 16384 floats per h buffer
#define SB (BB * PSTR)                       // 16384 per stats buffer

__device__ __forceinline__ void st_agent(float* p, float v) {
  __hip_atomic_store(p, v, __ATOMIC_RELAXED, __HIP_MEMORY_SCOPE_AGENT);
}
__device__ __forceinline__ void st_agent_i(int* p, int v) {
  __hip_atomic_store(p, v, __ATOMIC_RELAXED, __HIP_MEMORY_SCOPE_AGENT);
}

// ---------------------------------------------------------------------------
// Setup: tiled transpose W_out (V,H) -> Wt_out (H,V)
// ---------------------------------------------------------------------------
__global__ __launch_bounds__(256) void k_transpose_out(
    const float* __restrict__ W, float* __restrict__ Wt) {
  __shared__ float t[32][33];
  const int vb = blockIdx.x * 32;  // 1000
  const int kb = blockIdx.y * 32;  // 16
  const int c = threadIdx.x & 31, rq = threadIdx.x >> 5;
#pragma unroll
  for (int i = 0; i < 4; ++i) {
    int r = rq + i * 8;
    t[r][c] = W[(size_t)(vb + r) * HH + kb + c];
  }
  __syncthreads();
#pragma unroll
  for (int i = 0; i < 4; ++i) {
    int r = rq + i * 8;
    Wt[(size_t)(kb + r) * VV + vb + c] = t[c][r];
  }
}

// ---------------------------------------------------------------------------
// Setup: hseq[0] = encoder_hidden, scores = 0, seq col 0 = START(=1),
// barrier state zeroed.
// ---------------------------------------------------------------------------
__global__ __launch_bounds__(256) void k_init(
    const float* __restrict__ enc_h, float* __restrict__ h0,
    float* __restrict__ scores, int* __restrict__ tok_seq,
    unsigned* __restrict__ bar) {
  int idx = blockIdx.x * 256 + threadIdx.x;  // 64*256
  if (idx < BB * HH) h0[idx] = enc_h[idx];
  if (idx < BB) { scores[idx] = 0.0f; tok_seq[idx] = 1; }
  if (idx == 0) { bar[0] = 0u; bar[32] = 0u; }
}

// ---------------------------------------------------------------------------
// Flush-free grid barrier (R11-proven). bar[0]=count, bar[32]=generation.
// Relaxed agent atomics only (no buffer_inv/wbl2).
// ---------------------------------------------------------------------------
__device__ __forceinline__ void gbar(unsigned* bar, unsigned nblk) {
  __syncthreads();
  if (threadIdx.x == 0) {
    asm volatile("s_waitcnt vmcnt(0)" ::: "memory");
    unsigned g = __hip_atomic_load(&bar[32], __ATOMIC_RELAXED,
                                   __HIP_MEMORY_SCOPE_AGENT);
    asm volatile("s_waitcnt vmcnt(0)" ::: "memory");
    unsigned a = __hip_atomic_fetch_add(&bar[0], 1u, __ATOMIC_RELAXED,
                                        __HIP_MEMORY_SCOPE_AGENT);
    if (a == nblk - 1u) {
      __hip_atomic_store(&bar[0], 0u, __ATOMIC_RELAXED,
                         __HIP_MEMORY_SCOPE_AGENT);
      asm volatile("s_waitcnt vmcnt(0)" ::: "memory");
      __hip_atomic_fetch_add(&bar[32], 1u, __ATOMIC_RELAXED,
                             __HIP_MEMORY_SCOPE_AGENT);
    } else {
      while (__hip_atomic_load(&bar[32], __ATOMIC_RELAXED,
                               __HIP_MEMORY_SCOPE_AGENT) == g)
        __builtin_amdgcn_s_sleep(2);
    }
  }
  __syncthreads();
}

// ---------------------------------------------------------------------------
// FALLBACK global-load gemv body (R9-proven). Used only if cooperative
// launch is refused.
// ---------------------------------------------------------------------------
#define FMA4(accv, hscal, wv)              \
  accv.x = fmaf(hscal, wv.x, accv.x);      \
  accv.y = fmaf(hscal, wv.y, accv.y);      \
  accv.z = fmaf(hscal, wv.z, accv.z);      \
  accv.w = fmaf(hscal, wv.w, accv.w);

#define LOADG(W, g)                                                    \
  {                                                                    \
    const float* p_ = wp + (size_t)(g) * 8 * VV;                       \
    _Pragma("unroll") for (int j_ = 0; j_ < 8; ++j_)                   \
        W[j_] = *(const float4*)(p_ + (size_t)j_ * VV);                \
  }

#define COMPG(W, g)                                                    \
  {                                                                    \
    const int k0_ = (g) * 8;                                           \
    _Pragma("unroll") for (int jj_ = 0; jj_ < 2; ++jj_) {              \
      const float4 h0_ = *(const float4*)&hs[r0][k0_ + jj_ * 4];       \
      const float4 h1_ = *(const float4*)&hs[r0 + 1][k0_ + jj_ * 4];   \
      FMA4(acc0, h0_.x, W[jj_ * 4 + 0]);                               \
      FMA4(acc0, h0_.y, W[jj_ * 4 + 1]);                               \
      FMA4(acc0, h0_.z, W[jj_ * 4 + 2]);                               \
      FMA4(acc0, h0_.w, W[jj_ * 4 + 3]);                               \
      FMA4(acc1, h1_.x, W[jj_ * 4 + 0]);                               \
      FMA4(acc1, h1_.y, W[jj_ * 4 + 1]);                               \
      FMA4(acc1, h1_.z, W[jj_ * 4 + 2]);                               \
      FMA4(acc1, h1_.w, W[jj_ * 4 + 3]);                               \
    }                                                                  \
  }

__device__ __forceinline__ void gemv_body_glb(
    const int vb, const int tid, float* smem,
    const float* __restrict__ Wt, const float* __restrict__ hmat,
    const float* __restrict__ bout,
    float* __restrict__ pm, float* __restrict__ ps, int* __restrict__ pidx) {
  const int colq = tid & 15;
  const int rp = tid >> 4;
  const int r0 = rp * 2;
  const int col = vb * 64 + colq * 4;

  float (*hs)[516] = (float(*)[516])smem;
  {
    float4* hd = (float4*)smem;
    const float4* hp = (const float4*)hmat;
#pragma unroll
    for (int i = 0; i < 16; ++i) {
      const int idx = i * 256 + tid;
      const int r = idx >> 7, q = idx & 127;
      hd[r * 129 + q] = hp[idx];
    }
  }
  __syncthreads();

  const float* wp = Wt + col;
  float4 acc0 = {0.0f, 0.0f, 0.0f, 0.0f};
  float4 acc1 = {0.0f, 0.0f, 0.0f, 0.0f};

  float4 A[8], B[8], C[8];
  LOADG(A, 0);
  LOADG(B, 1);
#pragma unroll 1
  for (int g = 0; g < 63; g += 3) {
    LOADG(C, g + 2);
    COMPG(A, g);
    if (g + 3 < 64) LOADG(A, g + 3);
    COMPG(B, g + 1);
    if (g + 4 < 64) LOADG(B, g + 4);
    COMPG(C, g + 2);
  }
  COMPG(A, 63);

  {
    const float4 bo = *(const float4*)(bout + col);
    acc0.x += bo.x; acc0.y += bo.y; acc0.z += bo.z; acc0.w += bo.w;
    acc1.x += bo.x; acc1.y += bo.y; acc1.z += bo.z; acc1.w += bo.w;
  }

  const int lane = tid & 63;
  float m0 = acc0.x; int i0 = col;
  if (acc0.y > m0) { m0 = acc0.y; i0 = col + 1; }
  if (acc0.z > m0) { m0 = acc0.z; i0 = col + 2; }
  if (acc0.w > m0) { m0 = acc0.w; i0 = col + 3; }
  float m1 = acc1.x; int i1 = col;
  if (acc1.y > m1) { m1 = acc1.y; i1 = col + 1; }
  if (acc1.z > m1) { m1 = acc1.z; i1 = col + 2; }
  if (acc1.w > m1) { m1 = acc1.w; i1 = col + 3; }
#pragma unroll
  for (int off = 1; off < 16; off <<= 1) {
    const float om0 = __shfl_xor(m0, off);
    const int oi0 = __shfl_xor(i0, off);
    if (om0 > m0 || (om0 == m0 && oi0 < i0)) { m0 = om0; i0 = oi0; }
    const float om1 = __shfl_xor(m1, off);
    const int oi1 = __shfl_xor(i1, off);
    if (om1 > m1 || (om1 == m1 && oi1 < i1)) { m1 = om1; i1 = oi1; }
  }
  float s0 = __expf(acc0.x - m0) + __expf(acc0.y - m0) +
             __expf(acc0.z - m0) + __expf(acc0.w - m0);
  float s1 = __expf(acc1.x - m1) + __expf(acc1.y - m1) +
             __expf(acc1.z - m1) + __expf(acc1.w - m1);
#pragma unroll
  for (int off = 1; off < 16; off <<= 1) {
    s0 += __shfl_xor(s0, off);
    s1 += __shfl_xor(s1, off);
  }
  if ((lane & 15) == 0) {
    st_agent(&pm[r0 * PSTR + vb], m0);
    st_agent(&ps[r0 * PSTR + vb], s0);
    st_agent_i(&pidx[r0 * PSTR + vb], i0);
    st_agent(&pm[(r0 + 1) * PSTR + vb], m1);
    st_agent(&ps[(r0 + 1) * PSTR + vb], s1);
    st_agent_i(&pidx[(r0 + 1) * PSTR + vb], i1);
  }
}

// ---------------------------------------------------------------------------
// GRU step with fused token-select prologue (proven body). bid in 0..127:
// rg = bid>>4 (4 rows), jt = bid&15 (32 H-cols). step==TSTEPS: select only.
// ---------------------------------------------------------------------------
__device__ __forceinline__ void gru_body(
    const int bid, const int tid, const int step, float* smem, int* toks,
    const float* __restrict__ emb,
    const float* __restrict__ W_ih,   // (1536, 256) native
    const float* __restrict__ W_hh,   // (1536, 512) native
    const float* __restrict__ b_ih, const float* __restrict__ b_hh,
    const float* __restrict__ hin, float* __restrict__ hout,
    const float* __restrict__ pmt, const float* __restrict__ pst,
    const int* __restrict__ pidxt,
    float* __restrict__ scores, int* __restrict__ tok_seq) {
  const int rg = bid >> 4;   // 0..7
  const int jt = bid & 15;   // 0..15
  const int r0 = rg * 4, j0 = jt * 32;
  const int lane = tid & 63, wv = tid >> 6;  // wv 0..3

  float (*xs)[EE] = (float(*)[EE])smem;                 // 4*256
  float (*hsm)[HH] = (float(*)[HH])(smem + 4 * EE);     // 4*512
  float* gpart = smem + 4 * EE + 4 * HH;                // 24*272 = 6528

  if (step == 0) {
    if (tid < 4) toks[tid] = 1;  // START
  } else {
    const int row = r0 + wv;
    float mv[8], sv[8];
    int iv[8];
#pragma unroll
    for (int j = 0; j < 8; ++j) {
      const int ch = lane + 64 * j;
      const bool v = (ch < NCH);
      mv[j] = v ? pmt[row * PSTR + ch] : -FLT_MAX;
      sv[j] = v ? pst[row * PSTR + ch] : 0.0f;
      iv[j] = v ? pidxt[row * PSTR + ch] : 0x7fffffff;
    }
    float gm = mv[0];
    int gi = iv[0];
#pragma unroll
    for (int j = 1; j < 8; ++j)
      if (mv[j] > gm || (mv[j] == gm && iv[j] < gi)) { gm = mv[j]; gi = iv[j]; }
#pragma unroll
    for (int off = 1; off < 64; off <<= 1) {
      const float om = __shfl_xor(gm, off);
      const int oi = __shfl_xor(gi, off);
      if (om > gm || (om == gm && oi < gi)) { gm = om; gi = oi; }
    }
    float term = 0.0f;
#pragma unroll
    for (int j = 0; j < 8; ++j) term += sv[j] * __expf(mv[j] - gm);
#pragma unroll
    for (int off = 1; off < 64; off <<= 1) term += __shfl_xor(term, off);
    if (lane == 0) {
      toks[wv] = gi;
      if (jt == 0) {
        scores[row] -= logf(term);      // += max - logsumexp
        tok_seq[step * BB + row] = gi;  // seq column `step`
      }
    }
  }
  __syncthreads();
  if (step == TSTEPS) return;

  for (int i = tid; i < 4 * EE; i += 256) {
    const int r = i >> 8, c = i & (EE - 1);
    const float e = emb[(size_t)toks[r] * EE + c];
    xs[r][c] = e > 0.0f ? e : 0.0f;
  }
  for (int i = tid; i < 4 * HH; i += 256) {
    const int r = i >> 9, c = i & (HH - 1);
    hsm[r][c] = hin[(r0 + r) * HH + c];
  }
  __syncthreads();

  const int jh = tid & 31, kq = tid >> 5;  // 32 cols x 8 k-slices
  const int j = j0 + jh;
  float ai[3][4], ah[3][4];
#pragma unroll
  for (int g = 0; g < 3; ++g)
#pragma unroll
    for (int r = 0; r < 4; ++r) { ai[g][r] = 0.0f; ah[g][r] = 0.0f; }

#pragma unroll 2
  for (int q = 0; q < 8; ++q) {
    const int k4 = kq * 32 + q * 4;
    float4 xr[4];
#pragma unroll
    for (int r = 0; r < 4; ++r) xr[r] = *(const float4*)&xs[r][k4];
#pragma unroll
    for (int g = 0; g < 3; ++g) {
      const float4 w = *(const float4*)&W_ih[(size_t)(g * HH + j) * EE + k4];
#pragma unroll
      for (int r = 0; r < 4; ++r) {
        ai[g][r] = fmaf(xr[r].x, w.x, ai[g][r]);
        ai[g][r] = fmaf(xr[r].y, w.y, ai[g][r]);
        ai[g][r] = fmaf(xr[r].z, w.z, ai[g][r]);
        ai[g][r] = fmaf(xr[r].w, w.w, ai[g][r]);
      }
    }
  }
#pragma unroll 2
  for (int q = 0; q < 16; ++q) {
    const int k4 = kq * 64 + q * 4;
    float4 hr[4];
#pragma unroll
    for (int r = 0; r < 4; ++r) hr[r] = *(const float4*)&hsm[r][k4];
#pragma unroll
    for (int g = 0; g < 3; ++g) {
      const float4 w = *(const float4*)&W_hh[(size_t)(g * HH + j) * HH + k4];
#pragma unroll
      for (int r = 0; r < 4; ++r) {
        ah[g][r] = fmaf(hr[r].x, w.x, ah[g][r]);
        ah[g][r] = fmaf(hr[r].y, w.y, ah[g][r]);
        ah[g][r] = fmaf(hr[r].z, w.z, ah[g][r]);
        ah[g][r] = fmaf(hr[r].w, w.w, ah[g][r]);
      }
    }
  }
  {
    const int base = kq * 34 + jh;
#pragma unroll
    for (int g = 0; g < 3; ++g)
#pragma unroll
      for (int r = 0; r < 4; ++r) {
        gpart[(g * 4 + r) * 272 + base] = ai[g][r];
        gpart[(12 + g * 4 + r) * 272 + base] = ah[g][r];
      }
  }
  __syncthreads();

  if (tid < 128) {
    const int r = tid >> 5, jh2 = tid & 31;
    const int j2 = j0 + jh2;
    float g6[6];
#pragma unroll
    for (int c = 0; c < 6; ++c) {
      const int cc = (c < 3) ? (c * 4 + r) : (12 + (c - 3) * 4 + r);
      float s = 0.0f;
#pragma unroll
      for (int q = 0; q < 8; ++q) s += gpart[cc * 272 + q * 34 + jh2];
      g6[c] = s;
    }
    const float ir = g6[0] + b_ih[j2];
    const float iz = g6[1] + b_ih[HH + j2];
    const float in_ = g6[2] + b_ih[2 * HH + j2];
    const float hr_ = g6[3] + b_hh[j2];
    const float hz = g6[4] + b_hh[HH + j2];
    const float hn = g6[5] + b_hh[2 * HH + j2];
    const float rr = 1.0f / (1.0f + expf(-(ir + hr_)));
    const float zz = 1.0f / (1.0f + expf(-(iz + hz)));
    const float nn = tanhf(in_ + rr * hn);
    st_agent(&hout[(r0 + r) * HH + j2], (1.0f - zz) * nn + zz * hsm[r][j2]);
  }
}

// ---------------------------------------------------------------------------
// Persistent kernel with REGISTER-RESIDENT Wt. 512 blocks x 256 thr, 2/CU.
// Thread (c2 = tid&31, kq = tid>>5) of block vb holds wreg[64] = float2
// {Wt[k][vb*64 + c2*2], Wt[k][.. +1]} for k in kq*64..+63 (128 VGPRs,
// static indices only). Per step:
//   phase A (bid<128): select + GRU (proven body).  gbar.
//   phase B (vb<500): stage h[32][512] in LDS; per 8-row chunk: 1024 FMA
//     from wreg x LDS-broadcast h -> acc[8][2]; shfl_xor(32) merges kq
//     pairs; 8 KB LDS 4-way reduce; per-row max/argmax/sumexp over 32
//     lanes -> stats.  gbar.
// ---------------------------------------------------------------------------
__global__ __launch_bounds__(256, 2) void k_persist(
    const float* __restrict__ Wt, const float* __restrict__ emb,
    const float* __restrict__ W_ih, const float* __restrict__ W_hh,
    const float* __restrict__ b_ih, const float* __restrict__ b_hh,
    const float* __restrict__ bout,
    float* hseq, float* pmT, float* psT, int* pidxT,
    float* scores, int* tok_seq, unsigned* bar) {
  __shared__ __align__(16) float smem[SMEM_FLOATS];
  __shared__ int toks[4];
  const int bid = blockIdx.x, tid = threadIdx.x;
  const int c2 = tid & 31, kq = tid >> 5;  // 2 cols, 64-k slice
  const int vb = bid;                      // live if < NCH

  // ---- prologue: pin Wt slice in registers (once) ----
  float2 wreg[64];
  if (vb < NCH) {
    const float* wp = Wt + (size_t)(kq * 64) * VV + vb * 64 + c2 * 2;
#pragma unroll
    for (int k = 0; k < 64; ++k)
      wreg[k] = *(const float2*)(wp + (size_t)k * VV);
  } else {
#pragma unroll
    for (int k = 0; k < 64; ++k) wreg[k] = make_float2(0.0f, 0.0f);
  }
  // bias for this thread's 2 cols (constant across steps)
  float2 bo = make_float2(0.0f, 0.0f);
  if (vb < NCH) bo = *(const float2*)(bout + vb * 64 + c2 * 2);

  float* hs = smem;              // [32][512]
  float* part = smem + 16384;    // [4][8][64]

  for (int t = 0; t <= TSTEPS; ++t) {
    const float* hin = hseq + (size_t)t * HB;
    float* hout = hseq + (size_t)(t + 1) * HB;
    const int tp = (t > 0) ? (t - 1) : 0;
    // ---- phase A: select + GRU (select-only at t==TSTEPS) ----
    if (bid < 128)
      gru_body(bid, tid, t, smem, toks, emb, W_ih, W_hh, b_ih, b_hh,
               hin, hout, pmT + (size_t)tp * SB, psT + (size_t)tp * SB,
               pidxT + (size_t)tp * SB, scores, tok_seq);
    gbar(bar, 512u);
    if (t == TSTEPS) break;

    // ---- phase B: register-resident gemv + chunk stats ----
    if (vb < NCH) {
      float* pm = pmT + (size_t)t * SB;
      float* ps = psT + (size_t)t * SB;
      int* pidx = pidxT + (size_t)t * SB;
      // stage h (32x512, no pad needed: reads are 2-addr broadcasts)
      {
        float4* hd = (float4*)hs;
        const float4* hp = (const float4*)hout;
#pragma unroll
        for (int i = 0; i < 16; ++i) hd[i * 256 + tid] = hp[i * 256 + tid];
      }
      __syncthreads();

      const int w = tid >> 6;        // wave id 0..3
      const int rr = tid >> 5;       // reduce-stage row 0..7
      const int cp = tid & 31;       // reduce-stage col-pair
#pragma unroll 1
      for (int rc = 0; rc < 4; ++rc) {
        float acc0[8], acc1[8];
#pragma unroll
        for (int r = 0; r < 8; ++r) { acc0[r] = 0.0f; acc1[r] = 0.0f; }
#pragma unroll
        for (int r = 0; r < 8; ++r) {
          const float* hrow = hs + (rc * 8 + r) * 512 + kq * 64;
#pragma unroll
          for (int j = 0; j < 16; ++j) {
            const float4 h4 = *(const float4*)(hrow + j * 4);
            acc0[r] = fmaf(h4.x, wreg[j * 4 + 0].x, acc0[r]);
            acc1[r] = fmaf(h4.x, wreg[j * 4 + 0].y, acc1[r]);
            acc0[r] = fmaf(h4.y, wreg[j * 4 + 1].x, acc0[r]);
            acc1[r] = fmaf(h4.y, wreg[j * 4 + 1].y, acc1[r]);
            acc0[r] = fmaf(h4.z, wreg[j * 4 + 2].x, acc0[r]);
            acc1[r] = fmaf(h4.z, wreg[j * 4 + 2].y, acc1[r]);
            acc0[r] = fmaf(h4.w, wreg[j * 4 + 3].x, acc0[r]);
            acc1[r] = fmaf(h4.w, wreg[j * 4 + 3].y, acc1[r]);
          }
        }
        // merge kq pairs within wave (bit5)
#pragma unroll
        for (int r = 0; r < 8; ++r) {
          acc0[r] += __shfl_xor(acc0[r], 32);
          acc1[r] += __shfl_xor(acc1[r], 32);
        }
        if ((tid & 32) == 0) {   // lanes with even kq hold the pair sum
#pragma unroll
          for (int r = 0; r < 8; ++r) {
            float2* pp = (float2*)&part[w * 512 + r * 64 + c2 * 2];
            *pp = make_float2(acc0[r], acc1[r]);
          }
        }
        __syncthreads();
        // 4-way reduce + bias + per-row stats over 32 lanes
        {
          float l0 = 0.0f, l1 = 0.0f;
#pragma unroll
          for (int ww = 0; ww < 4; ++ww) {
            const float2 p = *(const float2*)&part[ww * 512 + rr * 64 + cp * 2];
            l0 += p.x; l1 += p.y;
          }
          const float2 bb = *(const float2*)(bout + vb * 64 + cp * 2);
          l0 += bb.x; l1 += bb.y;
          const int col0 = vb * 64 + cp * 2;
          float m = l0; int ii = col0;
          if (l1 > m) { m = l1; ii = col0 + 1; }
#pragma unroll
          for (int off = 1; off < 32; off <<= 1) {
            const float om = __shfl_xor(m, off);
            const int oi = __shfl_xor(ii, off);
            if (om > m || (om == m && oi < ii)) { m = om; ii = oi; }
          }
          float e = __expf(l0 - m) + __expf(l1 - m);
#pragma unroll
          for (int off = 1; off < 32; off <<= 1) e += __shfl_xor(e, off);
          if (cp == 0) {
            const int grow = rc * 8 + rr;
            st_agent(&pm[grow * PSTR + vb], m);
            st_agent(&ps[grow * PSTR + vb], e);
            st_agent_i(&pidx[grow * PSTR + vb], ii);
          }
        }
        __syncthreads();  // part reused next chunk
      }
    }
    gbar(bar, 512u);
  }
  (void)bo;
}

// ---------------------------------------------------------------------------
// Fallback standalone kernels (R9 path) — global-load bodies.
// ---------------------------------------------------------------------------
__global__ __launch_bounds__(256) void k_gemv_fused(
    const float* __restrict__ Wt, const float* __restrict__ hmat,
    const float* __restrict__ bout,
    float* __restrict__ pm, float* __restrict__ ps, int* __restrict__ pidx) {
  __shared__ __align__(16) float smem[16512];
  gemv_body_glb(blockIdx.x, threadIdx.x, smem, Wt, hmat, bout, pm, ps, pidx);
}

__global__ __launch_bounds__(256) void k_gru(
    const int step, const float* __restrict__ emb,
    const float* __restrict__ W_ih, const float* __restrict__ W_hh,
    const float* __restrict__ b_ih, const float* __restrict__ b_hh,
    const float* __restrict__ hin, float* __restrict__ hout,
    const float* __restrict__ pmt, const float* __restrict__ pst,
    const int* __restrict__ pidxt,
    float* __restrict__ scores, int* __restrict__ tok_seq) {
  __shared__ __align__(16) float smem[9600];
  __shared__ int toks[4];
  gru_body(blockIdx.x, threadIdx.x, step, smem, toks, emb, W_ih, W_hh,
           b_ih, b_hh, hin, hout, pmt, pst, pidxt, scores, tok_seq);
}

// ---------------------------------------------------------------------------
// Full-output writer: one-hot rows composed inline (no memset), h x3,
// scores x3. All stores float4, coalesced.
// ---------------------------------------------------------------------------
__global__ __launch_bounds__(256) void k_out(
    const int* __restrict__ tok_seq, const float* __restrict__ hfin,
    const float* __restrict__ scores, float* __restrict__ out) {
  const int blk = blockIdx.x, tid = threadIdx.x;
  if (blk < BB * (TSTEPS + 1)) {           // one (b,t) one-hot row
    const int b = blk / (TSTEPS + 1), t = blk % (TSTEPS + 1);
    const int tok = tok_seq[t * BB + b];
    const int tq = tok >> 2, tl = tok & 3;
    float4* op = (float4*)(out + (size_t)blk * VV);
    for (int i = tid; i < VV / 4; i += 256) {
      float4 z = {0.0f, 0.0f, 0.0f, 0.0f};
      if (i == tq) (&z.x)[tl] = 1.0f;
      op[i] = z;
    }
  } else if (blk < BB * (TSTEPS + 1) + 12) {  // h x3: 12288 float4
#pragma unroll
    for (int it = 0; it < 4; ++it) {
      const int idx = (blk - BB * (TSTEPS + 1)) * 1024 + it * 256 + tid;
      if (idx < H_ELEMS / 4) {
        const int fi = idx * 4;
        const int b = fi / (3 * HH);
        const int j0 = (fi % (3 * HH)) % HH;
        ((float4*)(out + DEC_ELEMS))[idx] =
            *(const float4*)(hfin + b * HH + j0);
      }
    }
  } else {                                   // scores x3: 96 floats
    if (tid < BB * 3) {
      out[(size_t)DEC_ELEMS + H_ELEMS + tid] = scores[tid / 3];
    }
  }
}

// ---------------------------------------------------------------------------
extern "C" void kernel_launch(void* const* d_in, const int* in_sizes, int n_in,
                              void* d_out, int out_size, void* d_ws, size_t ws_size,
                              hipStream_t stream) {
  const float* enc_h = (const float*)d_in[1];
  const float* emb   = (const float*)d_in[2];
  const float* W_ih  = (const float*)d_in[3];
  const float* W_hh  = (const float*)d_in[4];
  const float* b_ih  = (const float*)d_in[5];
  const float* b_hh  = (const float*)d_in[6];
  const float* W_out = (const float*)d_in[7];
  const float* b_out = (const float*)d_in[8];
  float* out = (float*)d_out;

  // workspace layout (floats) — ~74 MB total
  float* ws = (float*)d_ws;
  float* Wt_out  = ws;                        // 16,384,000
  float* hseq    = Wt_out + 16384000;         // 34 * 16384 (h after t steps)
  float* pmT     = hseq + 34 * HB;            // 32 * 16384 (per-step stats)
  float* psT     = pmT + 32 * SB;             // 32 * 16384
  float* scores  = psT + 32 * SB;             // 32
  int*   pidxT   = (int*)(scores + BB);       // 32 * 16384
  int*   tok_seq = pidxT + 32 * SB;           // 33*32
  unsigned* bar  = (unsigned*)(tok_seq + BB * (TSTEPS + 1));  // 64

  k_transpose_out<<<dim3(1000, 16), 256, 0, stream>>>(W_out, Wt_out);
  k_init<<<64, 256, 0, stream>>>(enc_h, hseq, scores, tok_seq, bar);

  // ---- persistent register-resident path (coop launch for co-residency) ----
  const float* Wt_c = Wt_out;
  void* args[] = {(void*)&Wt_c,  (void*)&emb,  (void*)&W_ih, (void*)&W_hh,
                  (void*)&b_ih,  (void*)&b_hh, (void*)&b_out,
                  (void*)&hseq,  (void*)&pmT,  (void*)&psT,  (void*)&pidxT,
                  (void*)&scores, (void*)&tok_seq, (void*)&bar};
  hipError_t ce = hipLaunchCooperativeKernel(
      reinterpret_cast<const void*>(&k_persist), dim3(512), dim3(256),
      args, 0u, stream);

  if (ce != hipSuccess) {
    // ---- fallback: multi-kernel path (global-load bodies) ----
    for (int t = 0; t < TSTEPS; ++t) {
      const int tp = (t > 0) ? (t - 1) : 0;
      k_gru<<<128, 256, 0, stream>>>(
          t, emb, W_ih, W_hh, b_ih, b_hh,
          hseq + (size_t)t * HB, hseq + (size_t)(t + 1) * HB,
          pmT + (size_t)tp * SB, psT + (size_t)tp * SB,
          pidxT + (size_t)tp * SB, scores, tok_seq);
      k_gemv_fused<<<NCH, 256, 0, stream>>>(
          Wt_out, hseq + (size_t)(t + 1) * HB, b_out,
          pmT + (size_t)t * SB, psT + (size_t)t * SB,
          pidxT + (size_t)t * SB);
    }
    k_gru<<<128, 256, 0, stream>>>(
        TSTEPS, emb, W_ih, W_hh, b_ih, b_hh,
        hseq + (size_t)TSTEPS * HB, hseq + (size_t)(TSTEPS + 1) * HB,
        pmT + (size_t)(TSTEPS - 1) * SB, psT + (size_t)(TSTEPS - 1) * SB,
        pidxT + (size_t)(TSTEPS - 1) * SB, scores, tok_seq);
  }

  // final h = hseq[32]; full-output writer
  k_out<<<BB * (TSTEPS + 1) + 13, 256, 0, stream>>>(
      tok_seq, hseq + (size_t)TSTEPS * HB, scores, out);
}

// Round 6
// 1604.642 us; speedup vs baseline: 5.6381x; 1.1088x over previous
//
#include <hip/hip_runtime.h>
#include <float.h>
#include <math.h>

// ============================================================================
// BeamSearchDecoder — MI355X. Greedy-equivalence: h0 = repeat(enc_h,K) and
// scores0 = 0 make all K=3 beams identical; top-3 of the 9 candidates = three
// copies of the argmax, so every beam takes the greedy token forever.
// decoded = one-hot(greedy seq), h = final greedy h x3, scores = cumulative
// (max - logsumexp) x3. All logits math fp32.
//
// R13 vs R12 (1779; k_persist 1622 = 49 us/step, FETCH 68 MB = Wt once):
// register-pinned Wt killed weight traffic; residual ~25-30 us/step is the
// two 512-block gbars (512 same-line atomics + 512 pollers on one line).
// R13: NO rendezvous. Per-step buffers mean no WAR hazard, so sync reduces
// to producer-count flags: gemv waits for 128 GRU h-arrivals; GRU waits for
// 500 gemv stats-arrivals. Two-level arrival (8 group lines -> root) +
// 8-line fan-out release, ~64 pollers/line, step-indexed slots (no reset).
// Visibility recipe identical to R11/R12 (sc1 stores, syncthreads-drain,
// first-touch plain reads). Compute bodies unchanged from R12.
// Fallback: R9 multi-kernel path (global-load gemv) if coop launch refused.
// ============================================================================

#define BB 32
#define HH 512
#define EE 256
#define VV 32000
#define TSTEPS 32
#define NCH 500                              // 64-col chunks (exact: 500*64)
#define PSTR 512                             // pm/ps/pidx row stride
#define DEC_ELEMS (BB * (TSTEPS + 1) * VV)   // 33,792,000
#define H_ELEMS (BB * 3 * HH)                // 49,152
#define SMEM_FLOATS 18432                    // hs 32*512 + part 4*8*64
#define HB (BB * HH)                         // 16384 floats per h buffer
#define SB (BB * PSTR)                       // 16384 per stats buffer
#define SLOT_U 1024                          // uints per sync slot
#define NSLOT 64                             // hslot[0..31], sslot[0..31]

__device__ __forceinline__ void st_agent(float* p, float v) {
  __hip_atomic_store(p, v, __ATOMIC_RELAXED, __HIP_MEMORY_SCOPE_AGENT);
}
__device__ __forceinline__ void st_agent_i(int* p, int v) {
  __hip_atomic_store(p, v, __ATOMIC_RELAXED, __HIP_MEMORY_SCOPE_AGENT);
}

// ---------------------------------------------------------------------------
// Two-level producer sync. Slot layout (uints): arr[g] at g*32, root at 256,
// rel[g] at 512+g*32 — every counter on its own 128 B line.
// ---------------------------------------------------------------------------
__device__ __forceinline__ void sync_arrive(unsigned* slot, int g,
                                            unsigned gtgt) {
  __syncthreads();  // all waves drained vmcnt -> block's sc1 data visible
  if (threadIdx.x == 0) {
    asm volatile("s_waitcnt vmcnt(0)" ::: "memory");
    unsigned a = __hip_atomic_fetch_add(&slot[g * 32], 1u, __ATOMIC_RELAXED,
                                        __HIP_MEMORY_SCOPE_AGENT);
    if (a == gtgt - 1u) {
      unsigned r = __hip_atomic_fetch_add(&slot[256], 1u, __ATOMIC_RELAXED,
                                          __HIP_MEMORY_SCOPE_AGENT);
      if (r == 7u) {
#pragma unroll
        for (int i = 0; i < 8; ++i)
          __hip_atomic_store(&slot[512 + i * 32], 1u, __ATOMIC_RELAXED,
                             __HIP_MEMORY_SCOPE_AGENT);
      }
    }
  }
}

__device__ __forceinline__ void sync_wait(unsigned* slot, int g) {
  if (threadIdx.x == 0) {
    while (__hip_atomic_load(&slot[512 + g * 32], __ATOMIC_RELAXED,
                             __HIP_MEMORY_SCOPE_AGENT) == 0u)
      __builtin_amdgcn_s_sleep(4);
  }
  __syncthreads();
}

// ---------------------------------------------------------------------------
// Setup: tiled transpose W_out (V,H) -> Wt_out (H,V)
// ---------------------------------------------------------------------------
__global__ __launch_bounds__(256) void k_transpose_out(
    const float* __restrict__ W, float* __restrict__ Wt) {
  __shared__ float t[32][33];
  const int vb = blockIdx.x * 32;  // 1000
  const int kb = blockIdx.y * 32;  // 16
  const int c = threadIdx.x & 31, rq = threadIdx.x >> 5;
#pragma unroll
  for (int i = 0; i < 4; ++i) {
    int r = rq + i * 8;
    t[r][c] = W[(size_t)(vb + r) * HH + kb + c];
  }
  __syncthreads();
#pragma unroll
  for (int i = 0; i < 4; ++i) {
    int r = rq + i * 8;
    Wt[(size_t)(kb + r) * VV + vb + c] = t[c][r];
  }
}

// ---------------------------------------------------------------------------
// Setup: hseq[0] = encoder_hidden, scores = 0, seq col 0 = START(=1),
// all sync slots zeroed.
// ---------------------------------------------------------------------------
__global__ __launch_bounds__(256) void k_init(
    const float* __restrict__ enc_h, float* __restrict__ h0,
    float* __restrict__ scores, int* __restrict__ tok_seq,
    unsigned* __restrict__ sync) {
  int idx = blockIdx.x * 256 + threadIdx.x;  // 64*256 = 16384
  if (idx < BB * HH) h0[idx] = enc_h[idx];
  if (idx < BB) { scores[idx] = 0.0f; tok_seq[idx] = 1; }
  for (int i = idx; i < NSLOT * SLOT_U; i += 16384) sync[i] = 0u;
}

// ---------------------------------------------------------------------------
// FALLBACK global-load gemv body (R9-proven). Used only if cooperative
// launch is refused.
// ---------------------------------------------------------------------------
#define FMA4(accv, hscal, wv)              \
  accv.x = fmaf(hscal, wv.x, accv.x);      \
  accv.y = fmaf(hscal, wv.y, accv.y);      \
  accv.z = fmaf(hscal, wv.z, accv.z);      \
  accv.w = fmaf(hscal, wv.w, accv.w);

#define LOADG(W, g)                                                    \
  {                                                                    \
    const float* p_ = wp + (size_t)(g) * 8 * VV;                       \
    _Pragma("unroll") for (int j_ = 0; j_ < 8; ++j_)                   \
        W[j_] = *(const float4*)(p_ + (size_t)j_ * VV);                \
  }

#define COMPG(W, g)                                                    \
  {                                                                    \
    const int k0_ = (g) * 8;                                           \
    _Pragma("unroll") for (int jj_ = 0; jj_ < 2; ++jj_) {              \
      const float4 h0_ = *(const float4*)&hs[r0][k0_ + jj_ * 4];       \
      const float4 h1_ = *(const float4*)&hs[r0 + 1][k0_ + jj_ * 4];   \
      FMA4(acc0, h0_.x, W[jj_ * 4 + 0]);                               \
      FMA4(acc0, h0_.y, W[jj_ * 4 + 1]);                               \
      FMA4(acc0, h0_.z, W[jj_ * 4 + 2]);                               \
      FMA4(acc0, h0_.w, W[jj_ * 4 + 3]);                               \
      FMA4(acc1, h1_.x, W[jj_ * 4 + 0]);                               \
      FMA4(acc1, h1_.y, W[jj_ * 4 + 1]);                               \
      FMA4(acc1, h1_.z, W[jj_ * 4 + 2]);                               \
      FMA4(acc1, h1_.w, W[jj_ * 4 + 3]);                               \
    }                                                                  \
  }

__device__ __forceinline__ void gemv_body_glb(
    const int vb, const int tid, float* smem,
    const float* __restrict__ Wt, const float* __restrict__ hmat,
    const float* __restrict__ bout,
    float* __restrict__ pm, float* __restrict__ ps, int* __restrict__ pidx) {
  const int colq = tid & 15;
  const int rp = tid >> 4;
  const int r0 = rp * 2;
  const int col = vb * 64 + colq * 4;

  float (*hs)[516] = (float(*)[516])smem;
  {
    float4* hd = (float4*)smem;
    const float4* hp = (const float4*)hmat;
#pragma unroll
    for (int i = 0; i < 16; ++i) {
      const int idx = i * 256 + tid;
      const int r = idx >> 7, q = idx & 127;
      hd[r * 129 + q] = hp[idx];
    }
  }
  __syncthreads();

  const float* wp = Wt + col;
  float4 acc0 = {0.0f, 0.0f, 0.0f, 0.0f};
  float4 acc1 = {0.0f, 0.0f, 0.0f, 0.0f};

  float4 A[8], B[8], C[8];
  LOADG(A, 0);
  LOADG(B, 1);
#pragma unroll 1
  for (int g = 0; g < 63; g += 3) {
    LOADG(C, g + 2);
    COMPG(A, g);
    if (g + 3 < 64) LOADG(A, g + 3);
    COMPG(B, g + 1);
    if (g + 4 < 64) LOADG(B, g + 4);
    COMPG(C, g + 2);
  }
  COMPG(A, 63);

  {
    const float4 bo = *(const float4*)(bout + col);
    acc0.x += bo.x; acc0.y += bo.y; acc0.z += bo.z; acc0.w += bo.w;
    acc1.x += bo.x; acc1.y += bo.y; acc1.z += bo.z; acc1.w += bo.w;
  }

  const int lane = tid & 63;
  float m0 = acc0.x; int i0 = col;
  if (acc0.y > m0) { m0 = acc0.y; i0 = col + 1; }
  if (acc0.z > m0) { m0 = acc0.z; i0 = col + 2; }
  if (acc0.w > m0) { m0 = acc0.w; i0 = col + 3; }
  float m1 = acc1.x; int i1 = col;
  if (acc1.y > m1) { m1 = acc1.y; i1 = col + 1; }
  if (acc1.z > m1) { m1 = acc1.z; i1 = col + 2; }
  if (acc1.w > m1) { m1 = acc1.w; i1 = col + 3; }
#pragma unroll
  for (int off = 1; off < 16; off <<= 1) {
    const float om0 = __shfl_xor(m0, off);
    const int oi0 = __shfl_xor(i0, off);
    if (om0 > m0 || (om0 == m0 && oi0 < i0)) { m0 = om0; i0 = oi0; }
    const float om1 = __shfl_xor(m1, off);
    const int oi1 = __shfl_xor(i1, off);
    if (om1 > m1 || (om1 == m1 && oi1 < i1)) { m1 = om1; i1 = oi1; }
  }
  float s0 = __expf(acc0.x - m0) + __expf(acc0.y - m0) +
             __expf(acc0.z - m0) + __expf(acc0.w - m0);
  float s1 = __expf(acc1.x - m1) + __expf(acc1.y - m1) +
             __expf(acc1.z - m1) + __expf(acc1.w - m1);
#pragma unroll
  for (int off = 1; off < 16; off <<= 1) {
    s0 += __shfl_xor(s0, off);
    s1 += __shfl_xor(s1, off);
  }
  if ((lane & 15) == 0) {
    st_agent(&pm[r0 * PSTR + vb], m0);
    st_agent(&ps[r0 * PSTR + vb], s0);
    st_agent_i(&pidx[r0 * PSTR + vb], i0);
    st_agent(&pm[(r0 + 1) * PSTR + vb], m1);
    st_agent(&ps[(r0 + 1) * PSTR + vb], s1);
    st_agent_i(&pidx[(r0 + 1) * PSTR + vb], i1);
  }
}

// ---------------------------------------------------------------------------
// GRU step with fused token-select prologue (proven body). bid in 0..127:
// rg = bid>>4 (4 rows), jt = bid&15 (32 H-cols). step==TSTEPS: select only.
// ---------------------------------------------------------------------------
__device__ __forceinline__ void gru_body(
    const int bid, const int tid, const int step, float* smem, int* toks,
    const float* __restrict__ emb,
    const float* __restrict__ W_ih,   // (1536, 256) native
    const float* __restrict__ W_hh,   // (1536, 512) native
    const float* __restrict__ b_ih, const float* __restrict__ b_hh,
    const float* __restrict__ hin, float* __restrict__ hout,
    const float* __restrict__ pmt, const float* __restrict__ pst,
    const int* __restrict__ pidxt,
    float* __restrict__ scores, int* __restrict__ tok_seq) {
  const int rg = bid >> 4;   // 0..7
  const int jt = bid & 15;   // 0..15
  const int r0 = rg * 4, j0 = jt * 32;
  const int lane = tid & 63, wv = tid >> 6;  // wv 0..3

  float (*xs)[EE] = (float(*)[EE])smem;                 // 4*256
  float (*hsm)[HH] = (float(*)[HH])(smem + 4 * EE);     // 4*512
  float* gpart = smem + 4 * EE + 4 * HH;                // 24*272 = 6528

  if (step == 0) {
    if (tid < 4) toks[tid] = 1;  // START
  } else {
    const int row = r0 + wv;
    float mv[8], sv[8];
    int iv[8];
#pragma unroll
    for (int j = 0; j < 8; ++j) {
      const int ch = lane + 64 * j;
      const bool v = (ch < NCH);
      mv[j] = v ? pmt[row * PSTR + ch] : -FLT_MAX;
      sv[j] = v ? pst[row * PSTR + ch] : 0.0f;
      iv[j] = v ? pidxt[row * PSTR + ch] : 0x7fffffff;
    }
    float gm = mv[0];
    int gi = iv[0];
#pragma unroll
    for (int j = 1; j < 8; ++j)
      if (mv[j] > gm || (mv[j] == gm && iv[j] < gi)) { gm = mv[j]; gi = iv[j]; }
#pragma unroll
    for (int off = 1; off < 64; off <<= 1) {
      const float om = __shfl_xor(gm, off);
      const int oi = __shfl_xor(gi, off);
      if (om > gm || (om == gm && oi < gi)) { gm = om; gi = oi; }
    }
    float term = 0.0f;
#pragma unroll
    for (int j = 0; j < 8; ++j) term += sv[j] * __expf(mv[j] - gm);
#pragma unroll
    for (int off = 1; off < 64; off <<= 1) term += __shfl_xor(term, off);
    if (lane == 0) {
      toks[wv] = gi;
      if (jt == 0) {
        scores[row] -= logf(term);      // += max - logsumexp
        tok_seq[step * BB + row] = gi;  // seq column `step`
      }
    }
  }
  __syncthreads();
  if (step == TSTEPS) return;

  for (int i = tid; i < 4 * EE; i += 256) {
    const int r = i >> 8, c = i & (EE - 1);
    const float e = emb[(size_t)toks[r] * EE + c];
    xs[r][c] = e > 0.0f ? e : 0.0f;
  }
  for (int i = tid; i < 4 * HH; i += 256) {
    const int r = i >> 9, c = i & (HH - 1);
    hsm[r][c] = hin[(r0 + r) * HH + c];
  }
  __syncthreads();

  const int jh = tid & 31, kq = tid >> 5;  // 32 cols x 8 k-slices
  const int j = j0 + jh;
  float ai[3][4], ah[3][4];
#pragma unroll
  for (int g = 0; g < 3; ++g)
#pragma unroll
    for (int r = 0; r < 4; ++r) { ai[g][r] = 0.0f; ah[g][r] = 0.0f; }

#pragma unroll 2
  for (int q = 0; q < 8; ++q) {
    const int k4 = kq * 32 + q * 4;
    float4 xr[4];
#pragma unroll
    for (int r = 0; r < 4; ++r) xr[r] = *(const float4*)&xs[r][k4];
#pragma unroll
    for (int g = 0; g < 3; ++g) {
      const float4 w = *(const float4*)&W_ih[(size_t)(g * HH + j) * EE + k4];
#pragma unroll
      for (int r = 0; r < 4; ++r) {
        ai[g][r] = fmaf(xr[r].x, w.x, ai[g][r]);
        ai[g][r] = fmaf(xr[r].y, w.y, ai[g][r]);
        ai[g][r] = fmaf(xr[r].z, w.z, ai[g][r]);
        ai[g][r] = fmaf(xr[r].w, w.w, ai[g][r]);
      }
    }
  }
#pragma unroll 2
  for (int q = 0; q < 16; ++q) {
    const int k4 = kq * 64 + q * 4;
    float4 hr[4];
#pragma unroll
    for (int r = 0; r < 4; ++r) hr[r] = *(const float4*)&hsm[r][k4];
#pragma unroll
    for (int g = 0; g < 3; ++g) {
      const float4 w = *(const float4*)&W_hh[(size_t)(g * HH + j) * HH + k4];
#pragma unroll
      for (int r = 0; r < 4; ++r) {
        ah[g][r] = fmaf(hr[r].x, w.x, ah[g][r]);
        ah[g][r] = fmaf(hr[r].y, w.y, ah[g][r]);
        ah[g][r] = fmaf(hr[r].z, w.z, ah[g][r]);
        ah[g][r] = fmaf(hr[r].w, w.w, ah[g][r]);
      }
    }
  }
  {
    const int base = kq * 34 + jh;
#pragma unroll
    for (int g = 0; g < 3; ++g)
#pragma unroll
      for (int r = 0; r < 4; ++r) {
        gpart[(g * 4 + r) * 272 + base] = ai[g][r];
        gpart[(12 + g * 4 + r) * 272 + base] = ah[g][r];
      }
  }
  __syncthreads();

  if (tid < 128) {
    const int r = tid >> 5, jh2 = tid & 31;
    const int j2 = j0 + jh2;
    float g6[6];
#pragma unroll
    for (int c = 0; c < 6; ++c) {
      const int cc = (c < 3) ? (c * 4 + r) : (12 + (c - 3) * 4 + r);
      float s = 0.0f;
#pragma unroll
      for (int q = 0; q < 8; ++q) s += gpart[cc * 272 + q * 34 + jh2];
      g6[c] = s;
    }
    const float ir = g6[0] + b_ih[j2];
    const float iz = g6[1] + b_ih[HH + j2];
    const float in_ = g6[2] + b_ih[2 * HH + j2];
    const float hr_ = g6[3] + b_hh[j2];
    const float hz = g6[4] + b_hh[HH + j2];
    const float hn = g6[5] + b_hh[2 * HH + j2];
    const float rr = 1.0f / (1.0f + expf(-(ir + hr_)));
    const float zz = 1.0f / (1.0f + expf(-(iz + hz)));
    const float nn = tanhf(in_ + rr * hn);
    st_agent(&hout[(r0 + r) * HH + j2], (1.0f - zz) * nn + zz * hsm[r][j2]);
  }
}

// ---------------------------------------------------------------------------
// Persistent kernel, REGISTER-RESIDENT Wt (R12-proven) + producer-flag sync.
// 512 blocks x 256 thr, 2/CU. hslot[t] (slot t): 128 GRU producers, groups
// of 16 (bid>>4). sslot[t] (slot 32+t): 500 gemv producers, groups of 64
// (bid>>6), last group 52. Pollers poll release line (bid&7). No rendezvous.
// ---------------------------------------------------------------------------
__global__ __launch_bounds__(256, 2) void k_persist(
    const float* __restrict__ Wt, const float* __restrict__ emb,
    const float* __restrict__ W_ih, const float* __restrict__ W_hh,
    const float* __restrict__ b_ih, const float* __restrict__ b_hh,
    const float* __restrict__ bout,
    float* hseq, float* pmT, float* psT, int* pidxT,
    float* scores, int* tok_seq, unsigned* sync) {
  __shared__ __align__(16) float smem[SMEM_FLOATS];
  __shared__ int toks[4];
  const int bid = blockIdx.x, tid = threadIdx.x;
  const int c2 = tid & 31, kq = tid >> 5;  // 2 cols, 64-k slice
  const int vb = bid;                      // live if < NCH

  // ---- prologue: pin Wt slice in registers (once) ----
  float2 wreg[64];
  if (vb < NCH) {
    const float* wp = Wt + (size_t)(kq * 64) * VV + vb * 64 + c2 * 2;
#pragma unroll
    for (int k = 0; k < 64; ++k)
      wreg[k] = *(const float2*)(wp + (size_t)k * VV);
  } else {
#pragma unroll
    for (int k = 0; k < 64; ++k) wreg[k] = make_float2(0.0f, 0.0f);
  }

  float* hs = smem;              // [32][512]
  float* part = smem + 16384;    // [4][8][64]

  for (int t = 0; t <= TSTEPS; ++t) {
    const float* hin = hseq + (size_t)t * HB;
    float* hout = hseq + (size_t)(t + 1) * HB;
    const int tp = (t > 0) ? (t - 1) : 0;

    // ---- phase A: select + GRU (select-only at t==TSTEPS) ----
    if (bid < 128) {
      if (t > 0) sync_wait(sync + (size_t)(32 + tp) * SLOT_U, bid & 7);
      gru_body(bid, tid, t, smem, toks, emb, W_ih, W_hh, b_ih, b_hh,
               hin, hout, pmT + (size_t)tp * SB, psT + (size_t)tp * SB,
               pidxT + (size_t)tp * SB, scores, tok_seq);
      if (t < TSTEPS)
        sync_arrive(sync + (size_t)t * SLOT_U, bid >> 4, 16u);
    }
    if (t == TSTEPS) break;

    // ---- phase B: register-resident gemv + chunk stats ----
    if (vb < NCH) {
      sync_wait(sync + (size_t)t * SLOT_U, bid & 7);
      float* pm = pmT + (size_t)t * SB;
      float* ps = psT + (size_t)t * SB;
      int* pidx = pidxT + (size_t)t * SB;
      // stage h (32x512)
      {
        float4* hd = (float4*)hs;
        const float4* hp = (const float4*)hout;
#pragma unroll
        for (int i = 0; i < 16; ++i) hd[i * 256 + tid] = hp[i * 256 + tid];
      }
      __syncthreads();

      const int w = tid >> 6;        // wave id 0..3
      const int rr = tid >> 5;       // reduce-stage row 0..7
      const int cp = tid & 31;       // reduce-stage col-pair
#pragma unroll 1
      for (int rc = 0; rc < 4; ++rc) {
        float acc0[8], acc1[8];
#pragma unroll
        for (int r = 0; r < 8; ++r) { acc0[r] = 0.0f; acc1[r] = 0.0f; }
#pragma unroll
        for (int r = 0; r < 8; ++r) {
          const float* hrow = hs + (rc * 8 + r) * 512 + kq * 64;
#pragma unroll
          for (int j = 0; j < 16; ++j) {
            const float4 h4 = *(const float4*)(hrow + j * 4);
            acc0[r] = fmaf(h4.x, wreg[j * 4 + 0].x, acc0[r]);
            acc1[r] = fmaf(h4.x, wreg[j * 4 + 0].y, acc1[r]);
            acc0[r] = fmaf(h4.y, wreg[j * 4 + 1].x, acc0[r]);
            acc1[r] = fmaf(h4.y, wreg[j * 4 + 1].y, acc1[r]);
            acc0[r] = fmaf(h4.z, wreg[j * 4 + 2].x, acc0[r]);
            acc1[r] = fmaf(h4.z, wreg[j * 4 + 2].y, acc1[r]);
            acc0[r] = fmaf(h4.w, wreg[j * 4 + 3].x, acc0[r]);
            acc1[r] = fmaf(h4.w, wreg[j * 4 + 3].y, acc1[r]);
          }
        }
        // merge kq pairs within wave (bit5)
#pragma unroll
        for (int r = 0; r < 8; ++r) {
          acc0[r] += __shfl_xor(acc0[r], 32);
          acc1[r] += __shfl_xor(acc1[r], 32);
        }
        if ((tid & 32) == 0) {   // lanes with even kq hold the pair sum
#pragma unroll
          for (int r = 0; r < 8; ++r) {
            float2* pp = (float2*)&part[w * 512 + r * 64 + c2 * 2];
            *pp = make_float2(acc0[r], acc1[r]);
          }
        }
        __syncthreads();
        // 4-way reduce + bias + per-row stats over 32 lanes
        {
          float l0 = 0.0f, l1 = 0.0f;
#pragma unroll
          for (int ww = 0; ww < 4; ++ww) {
            const float2 p = *(const float2*)&part[ww * 512 + rr * 64 + cp * 2];
            l0 += p.x; l1 += p.y;
          }
          const float2 bb = *(const float2*)(bout + vb * 64 + cp * 2);
          l0 += bb.x; l1 += bb.y;
          const int col0 = vb * 64 + cp * 2;
          float m = l0; int ii = col0;
          if (l1 > m) { m = l1; ii = col0 + 1; }
#pragma unroll
          for (int off = 1; off < 32; off <<= 1) {
            const float om = __shfl_xor(m, off);
            const int oi = __shfl_xor(ii, off);
            if (om > m || (om == m && oi < ii)) { m = om; ii = oi; }
          }
          float e = __expf(l0 - m) + __expf(l1 - m);
#pragma unroll
          for (int off = 1; off < 32; off <<= 1) e += __shfl_xor(e, off);
          if (cp == 0) {
            const int grow = rc * 8 + rr;
            st_agent(&pm[grow * PSTR + vb], m);
            st_agent(&ps[grow * PSTR + vb], e);
            st_agent_i(&pidx[grow * PSTR + vb], ii);
          }
        }
        __syncthreads();  // part reused next chunk
      }
      sync_arrive(sync + (size_t)(32 + t) * SLOT_U, bid >> 6,
                  (bid >> 6) < 7 ? 64u : 52u);
    }
  }
}

// ---------------------------------------------------------------------------
// Fallback standalone kernels (R9 path) — global-load bodies.
// ---------------------------------------------------------------------------
__global__ __launch_bounds__(256) void k_gemv_fused(
    const float* __restrict__ Wt, const float* __restrict__ hmat,
    const float* __restrict__ bout,
    float* __restrict__ pm, float* __restrict__ ps, int* __restrict__ pidx) {
  __shared__ __align__(16) float smem[16512];
  gemv_body_glb(blockIdx.x, threadIdx.x, smem, Wt, hmat, bout, pm, ps, pidx);
}

__global__ __launch_bounds__(256) void k_gru(
    const int step, const float* __restrict__ emb,
    const float* __restrict__ W_ih, const float* __restrict__ W_hh,
    const float* __restrict__ b_ih, const float* __restrict__ b_hh,
    const float* __restrict__ hin, float* __restrict__ hout,
    const float* __restrict__ pmt, const float* __restrict__ pst,
    const int* __restrict__ pidxt,
    float* __restrict__ scores, int* __restrict__ tok_seq) {
  __shared__ __align__(16) float smem[9600];
  __shared__ int toks[4];
  gru_body(blockIdx.x, threadIdx.x, step, smem, toks, emb, W_ih, W_hh,
           b_ih, b_hh, hin, hout, pmt, pst, pidxt, scores, tok_seq);
}

// ---------------------------------------------------------------------------
// Full-output writer: one-hot rows composed inline (no memset), h x3,
// scores x3. All stores float4, coalesced.
// ---------------------------------------------------------------------------
__global__ __launch_bounds__(256) void k_out(
    const int* __restrict__ tok_seq, const float* __restrict__ hfin,
    const float* __restrict__ scores, float* __restrict__ out) {
  const int blk = blockIdx.x, tid = threadIdx.x;
  if (blk < BB * (TSTEPS + 1)) {           // one (b,t) one-hot row
    const int b = blk / (TSTEPS + 1), t = blk % (TSTEPS + 1);
    const int tok = tok_seq[t * BB + b];
    const int tq = tok >> 2, tl = tok & 3;
    float4* op = (float4*)(out + (size_t)blk * VV);
    for (int i = tid; i < VV / 4; i += 256) {
      float4 z = {0.0f, 0.0f, 0.0f, 0.0f};
      if (i == tq) (&z.x)[tl] = 1.0f;
      op[i] = z;
    }
  } else if (blk < BB * (TSTEPS + 1) + 12) {  // h x3: 12288 float4
#pragma unroll
    for (int it = 0; it < 4; ++it) {
      const int idx = (blk - BB * (TSTEPS + 1)) * 1024 + it * 256 + tid;
      if (idx < H_ELEMS / 4) {
        const int fi = idx * 4;
        const int b = fi / (3 * HH);
        const int j0 = (fi % (3 * HH)) % HH;
        ((float4*)(out + DEC_ELEMS))[idx] =
            *(const float4*)(hfin + b * HH + j0);
      }
    }
  } else {                                   // scores x3: 96 floats
    if (tid < BB * 3) {
      out[(size_t)DEC_ELEMS + H_ELEMS + tid] = scores[tid / 3];
    }
  }
}

// ---------------------------------------------------------------------------
extern "C" void kernel_launch(void* const* d_in, const int* in_sizes, int n_in,
                              void* d_out, int out_size, void* d_ws, size_t ws_size,
                              hipStream_t stream) {
  const float* enc_h = (const float*)d_in[1];
  const float* emb   = (const float*)d_in[2];
  const float* W_ih  = (const float*)d_in[3];
  const float* W_hh  = (const float*)d_in[4];
  const float* b_ih  = (const float*)d_in[5];
  const float* b_hh  = (const float*)d_in[6];
  const float* W_out = (const float*)d_in[7];
  const float* b_out = (const float*)d_in[8];
  float* out = (float*)d_out;

  // workspace layout (floats) — ~74.5 MB total
  float* ws = (float*)d_ws;
  float* Wt_out  = ws;                        // 16,384,000
  float* hseq    = Wt_out + 16384000;         // 34 * 16384 (h after t steps)
  float* pmT     = hseq + 34 * HB;            // 32 * 16384 (per-step stats)
  float* psT     = pmT + 32 * SB;             // 32 * 16384
  float* scores  = psT + 32 * SB;             // 32
  int*   pidxT   = (int*)(scores + BB);       // 32 * 16384
  int*   tok_seq = pidxT + 32 * SB;           // 33*32
  unsigned* sync = (unsigned*)(tok_seq + BB * (TSTEPS + 1));  // 64*1024

  k_transpose_out<<<dim3(1000, 16), 256, 0, stream>>>(W_out, Wt_out);
  k_init<<<64, 256, 0, stream>>>(enc_h, hseq, scores, tok_seq, sync);

  // ---- persistent register-resident path (coop launch for co-residency) ----
  const float* Wt_c = Wt_out;
  void* args[] = {(void*)&Wt_c,  (void*)&emb,  (void*)&W_ih, (void*)&W_hh,
                  (void*)&b_ih,  (void*)&b_hh, (void*)&b_out,
                  (void*)&hseq,  (void*)&pmT,  (void*)&psT,  (void*)&pidxT,
                  (void*)&scores, (void*)&tok_seq, (void*)&sync};
  hipError_t ce = hipLaunchCooperativeKernel(
      reinterpret_cast<const void*>(&k_persist), dim3(512), dim3(256),
      args, 0u, stream);

  if (ce != hipSuccess) {
    // ---- fallback: multi-kernel path (global-load bodies) ----
    for (int t = 0; t < TSTEPS; ++t) {
      const int tp = (t > 0) ? (t - 1) : 0;
      k_gru<<<128, 256, 0, stream>>>(
          t, emb, W_ih, W_hh, b_ih, b_hh,
          hseq + (size_t)t * HB, hseq + (size_t)(t + 1) * HB,
          pmT + (size_t)tp * SB, psT + (size_t)tp * SB,
          pidxT + (size_t)tp * SB, scores, tok_seq);
      k_gemv_fused<<<NCH, 256, 0, stream>>>(
          Wt_out, hseq + (size_t)(t + 1) * HB, b_out,
          pmT + (size_t)t * SB, psT + (size_t)t * SB,
          pidxT + (size_t)t * SB);
    }
    k_gru<<<128, 256, 0, stream>>>(
        TSTEPS, emb, W_ih, W_hh, b_ih, b_hh,
        hseq + (size_t)TSTEPS * HB, hseq + (size_t)(TSTEPS + 1) * HB,
        pmT + (size_t)(TSTEPS - 1) * SB, psT + (size_t)(TSTEPS - 1) * SB,
        pidxT + (size_t)(TSTEPS - 1) * SB, scores, tok_seq);
  }

  // final h = hseq[32]; full-output writer
  k_out<<<BB * (TSTEPS + 1) + 13, 256, 0, stream>>>(
      tok_seq, hseq + (size_t)TSTEPS * HB, scores, out);
}

// Round 7
// 1591.687 us; speedup vs baseline: 5.6839x; 1.0081x over previous
//
#include <hip/hip_runtime.h>
#include <float.h>
#include <math.h>

// ============================================================================
// BeamSearchDecoder — MI355X. Greedy-equivalence: h0 = repeat(enc_h,K) and
// scores0 = 0 make all K=3 beams identical; top-3 of the 9 candidates = three
// copies of the argmax, so every beam takes the greedy token forever.
// decoded = one-hot(greedy seq), h = final greedy h x3, scores = cumulative
// (max - logsumexp) x3. All logits math fp32.
//
// R14 vs R13 (1604; k_persist 1441): counters proved wreg NEVER lived in
// registers — VGPR_Count=128 (= wreg alone) and WRITE_SIZE=51.7 MB (~45 MB
// scratch spill-out) => the allocator squeezed to 128 VGPRs and spilled
// wreg to scratch; the gemv inner loop was reloading 512 B/thread/rc from
// L2-cached scratch (same load count as the global-load gemv). R14 pins the
// occupancy exactly: amdgpu_waves_per_eu(2,2) + flat_work_group_size(256,256)
// -> allocator budget 256 VGPRs (still 2 blocks/CU with LDS 74 KB, coop
// launch OK); wreg(128) + working set (~100) fits => true register
// residency. Everything else identical to R13 (producer-flag sync,
// per-step buffers, sc1 visibility recipe, proven bodies).
// Fallback: R9 multi-kernel path (global-load gemv) if coop launch refused.
// ============================================================================

#define BB 32
#define HH 512
#define EE 256
#define VV 32000
#define TSTEPS 32
#define NCH 500                              // 64-col chunks (exact: 500*64)
#define PSTR 512                             // pm/ps/pidx row stride
#define DEC_ELEMS (BB * (TSTEPS + 1) * VV)   // 33,792,000
#define H_ELEMS (BB * 3 * HH)                // 49,152
#define SMEM_FLOATS 18432                    // hs 32*512 + part 4*8*64
#define HB (BB * HH)                         // 16384 floats per h buffer
#define SB (BB * PSTR)                       // 16384 per stats buffer
#define SLOT_U 1024                          // uints per sync slot
#define NSLOT 64                             // hslot[0..31], sslot[0..31]

__device__ __forceinline__ void st_agent(float* p, float v) {
  __hip_atomic_store(p, v, __ATOMIC_RELAXED, __HIP_MEMORY_SCOPE_AGENT);
}
__device__ __forceinline__ void st_agent_i(int* p, int v) {
  __hip_atomic_store(p, v, __ATOMIC_RELAXED, __HIP_MEMORY_SCOPE_AGENT);
}

// ---------------------------------------------------------------------------
// Two-level producer sync. Slot layout (uints): arr[g] at g*32, root at 256,
// rel[g] at 512+g*32 — every counter on its own 128 B line.
// ---------------------------------------------------------------------------
__device__ __forceinline__ void sync_arrive(unsigned* slot, int g,
                                            unsigned gtgt) {
  __syncthreads();  // all waves drained vmcnt -> block's sc1 data visible
  if (threadIdx.x == 0) {
    asm volatile("s_waitcnt vmcnt(0)" ::: "memory");
    unsigned a = __hip_atomic_fetch_add(&slot[g * 32], 1u, __ATOMIC_RELAXED,
                                        __HIP_MEMORY_SCOPE_AGENT);
    if (a == gtgt - 1u) {
      unsigned r = __hip_atomic_fetch_add(&slot[256], 1u, __ATOMIC_RELAXED,
                                          __HIP_MEMORY_SCOPE_AGENT);
      if (r == 7u) {
#pragma unroll
        for (int i = 0; i < 8; ++i)
          __hip_atomic_store(&slot[512 + i * 32], 1u, __ATOMIC_RELAXED,
                             __HIP_MEMORY_SCOPE_AGENT);
      }
    }
  }
}

__device__ __forceinline__ void sync_wait(unsigned* slot, int g) {
  if (threadIdx.x == 0) {
    while (__hip_atomic_load(&slot[512 + g * 32], __ATOMIC_RELAXED,
                             __HIP_MEMORY_SCOPE_AGENT) == 0u)
      __builtin_amdgcn_s_sleep(4);
  }
  __syncthreads();
}

// ---------------------------------------------------------------------------
// Setup: tiled transpose W_out (V,H) -> Wt_out (H,V)
// ---------------------------------------------------------------------------
__global__ __launch_bounds__(256) void k_transpose_out(
    const float* __restrict__ W, float* __restrict__ Wt) {
  __shared__ float t[32][33];
  const int vb = blockIdx.x * 32;  // 1000
  const int kb = blockIdx.y * 32;  // 16
  const int c = threadIdx.x & 31, rq = threadIdx.x >> 5;
#pragma unroll
  for (int i = 0; i < 4; ++i) {
    int r = rq + i * 8;
    t[r][c] = W[(size_t)(vb + r) * HH + kb + c];
  }
  __syncthreads();
#pragma unroll
  for (int i = 0; i < 4; ++i) {
    int r = rq + i * 8;
    Wt[(size_t)(kb + r) * VV + vb + c] = t[c][r];
  }
}

// ---------------------------------------------------------------------------
// Setup: hseq[0] = encoder_hidden, scores = 0, seq col 0 = START(=1),
// all sync slots zeroed.
// ---------------------------------------------------------------------------
__global__ __launch_bounds__(256) void k_init(
    const float* __restrict__ enc_h, float* __restrict__ h0,
    float* __restrict__ scores, int* __restrict__ tok_seq,
    unsigned* __restrict__ sync) {
  int idx = blockIdx.x * 256 + threadIdx.x;  // 64*256 = 16384
  if (idx < BB * HH) h0[idx] = enc_h[idx];
  if (idx < BB) { scores[idx] = 0.0f; tok_seq[idx] = 1; }
  for (int i = idx; i < NSLOT * SLOT_U; i += 16384) sync[i] = 0u;
}

// ---------------------------------------------------------------------------
// FALLBACK global-load gemv body (R9-proven). Used only if cooperative
// launch is refused.
// ---------------------------------------------------------------------------
#define FMA4(accv, hscal, wv)              \
  accv.x = fmaf(hscal, wv.x, accv.x);      \
  accv.y = fmaf(hscal, wv.y, accv.y);      \
  accv.z = fmaf(hscal, wv.z, accv.z);      \
  accv.w = fmaf(hscal, wv.w, accv.w);

#define LOADG(W, g)                                                    \
  {                                                                    \
    const float* p_ = wp + (size_t)(g) * 8 * VV;                       \
    _Pragma("unroll") for (int j_ = 0; j_ < 8; ++j_)                   \
        W[j_] = *(const float4*)(p_ + (size_t)j_ * VV);                \
  }

#define COMPG(W, g)                                                    \
  {                                                                    \
    const int k0_ = (g) * 8;                                           \
    _Pragma("unroll") for (int jj_ = 0; jj_ < 2; ++jj_) {              \
      const float4 h0_ = *(const float4*)&hs[r0][k0_ + jj_ * 4];       \
      const float4 h1_ = *(const float4*)&hs[r0 + 1][k0_ + jj_ * 4];   \
      FMA4(acc0, h0_.x, W[jj_ * 4 + 0]);                               \
      FMA4(acc0, h0_.y, W[jj_ * 4 + 1]);                               \
      FMA4(acc0, h0_.z, W[jj_ * 4 + 2]);                               \
      FMA4(acc0, h0_.w, W[jj_ * 4 + 3]);                               \
      FMA4(acc1, h1_.x, W[jj_ * 4 + 0]);                               \
      FMA4(acc1, h1_.y, W[jj_ * 4 + 1]);                               \
      FMA4(acc1, h1_.z, W[jj_ * 4 + 2]);                               \
      FMA4(acc1, h1_.w, W[jj_ * 4 + 3]);                               \
    }                                                                  \
  }

__device__ __forceinline__ void gemv_body_glb(
    const int vb, const int tid, float* smem,
    const float* __restrict__ Wt, const float* __restrict__ hmat,
    const float* __restrict__ bout,
    float* __restrict__ pm, float* __restrict__ ps, int* __restrict__ pidx) {
  const int colq = tid & 15;
  const int rp = tid >> 4;
  const int r0 = rp * 2;
  const int col = vb * 64 + colq * 4;

  float (*hs)[516] = (float(*)[516])smem;
  {
    float4* hd = (float4*)smem;
    const float4* hp = (const float4*)hmat;
#pragma unroll
    for (int i = 0; i < 16; ++i) {
      const int idx = i * 256 + tid;
      const int r = idx >> 7, q = idx & 127;
      hd[r * 129 + q] = hp[idx];
    }
  }
  __syncthreads();

  const float* wp = Wt + col;
  float4 acc0 = {0.0f, 0.0f, 0.0f, 0.0f};
  float4 acc1 = {0.0f, 0.0f, 0.0f, 0.0f};

  float4 A[8], B[8], C[8];
  LOADG(A, 0);
  LOADG(B, 1);
#pragma unroll 1
  for (int g = 0; g < 63; g += 3) {
    LOADG(C, g + 2);
    COMPG(A, g);
    if (g + 3 < 64) LOADG(A, g + 3);
    COMPG(B, g + 1);
    if (g + 4 < 64) LOADG(B, g + 4);
    COMPG(C, g + 2);
  }
  COMPG(A, 63);

  {
    const float4 bo = *(const float4*)(bout + col);
    acc0.x += bo.x; acc0.y += bo.y; acc0.z += bo.z; acc0.w += bo.w;
    acc1.x += bo.x; acc1.y += bo.y; acc1.z += bo.z; acc1.w += bo.w;
  }

  const int lane = tid & 63;
  float m0 = acc0.x; int i0 = col;
  if (acc0.y > m0) { m0 = acc0.y; i0 = col + 1; }
  if (acc0.z > m0) { m0 = acc0.z; i0 = col + 2; }
  if (acc0.w > m0) { m0 = acc0.w; i0 = col + 3; }
  float m1 = acc1.x; int i1 = col;
  if (acc1.y > m1) { m1 = acc1.y; i1 = col + 1; }
  if (acc1.z > m1) { m1 = acc1.z; i1 = col + 2; }
  if (acc1.w > m1) { m1 = acc1.w; i1 = col + 3; }
#pragma unroll
  for (int off = 1; off < 16; off <<= 1) {
    const float om0 = __shfl_xor(m0, off);
    const int oi0 = __shfl_xor(i0, off);
    if (om0 > m0 || (om0 == m0 && oi0 < i0)) { m0 = om0; i0 = oi0; }
    const float om1 = __shfl_xor(m1, off);
    const int oi1 = __shfl_xor(i1, off);
    if (om1 > m1 || (om1 == m1 && oi1 < i1)) { m1 = om1; i1 = oi1; }
  }
  float s0 = __expf(acc0.x - m0) + __expf(acc0.y - m0) +
             __expf(acc0.z - m0) + __expf(acc0.w - m0);
  float s1 = __expf(acc1.x - m1) + __expf(acc1.y - m1) +
             __expf(acc1.z - m1) + __expf(acc1.w - m1);
#pragma unroll
  for (int off = 1; off < 16; off <<= 1) {
    s0 += __shfl_xor(s0, off);
    s1 += __shfl_xor(s1, off);
  }
  if ((lane & 15) == 0) {
    st_agent(&pm[r0 * PSTR + vb], m0);
    st_agent(&ps[r0 * PSTR + vb], s0);
    st_agent_i(&pidx[r0 * PSTR + vb], i0);
    st_agent(&pm[(r0 + 1) * PSTR + vb], m1);
    st_agent(&ps[(r0 + 1) * PSTR + vb], s1);
    st_agent_i(&pidx[(r0 + 1) * PSTR + vb], i1);
  }
}

// ---------------------------------------------------------------------------
// GRU step with fused token-select prologue (proven body). bid in 0..127:
// rg = bid>>4 (4 rows), jt = bid&15 (32 H-cols). step==TSTEPS: select only.
// ---------------------------------------------------------------------------
__device__ __forceinline__ void gru_body(
    const int bid, const int tid, const int step, float* smem, int* toks,
    const float* __restrict__ emb,
    const float* __restrict__ W_ih,   // (1536, 256) native
    const float* __restrict__ W_hh,   // (1536, 512) native
    const float* __restrict__ b_ih, const float* __restrict__ b_hh,
    const float* __restrict__ hin, float* __restrict__ hout,
    const float* __restrict__ pmt, const float* __restrict__ pst,
    const int* __restrict__ pidxt,
    float* __restrict__ scores, int* __restrict__ tok_seq) {
  const int rg = bid >> 4;   // 0..7
  const int jt = bid & 15;   // 0..15
  const int r0 = rg * 4, j0 = jt * 32;
  const int lane = tid & 63, wv = tid >> 6;  // wv 0..3

  float (*xs)[EE] = (float(*)[EE])smem;                 // 4*256
  float (*hsm)[HH] = (float(*)[HH])(smem + 4 * EE);     // 4*512
  float* gpart = smem + 4 * EE + 4 * HH;                // 24*272 = 6528

  if (step == 0) {
    if (tid < 4) toks[tid] = 1;  // START
  } else {
    const int row = r0 + wv;
    float mv[8], sv[8];
    int iv[8];
#pragma unroll
    for (int j = 0; j < 8; ++j) {
      const int ch = lane + 64 * j;
      const bool v = (ch < NCH);
      mv[j] = v ? pmt[row * PSTR + ch] : -FLT_MAX;
      sv[j] = v ? pst[row * PSTR + ch] : 0.0f;
      iv[j] = v ? pidxt[row * PSTR + ch] : 0x7fffffff;
    }
    float gm = mv[0];
    int gi = iv[0];
#pragma unroll
    for (int j = 1; j < 8; ++j)
      if (mv[j] > gm || (mv[j] == gm && iv[j] < gi)) { gm = mv[j]; gi = iv[j]; }
#pragma unroll
    for (int off = 1; off < 64; off <<= 1) {
      const float om = __shfl_xor(gm, off);
      const int oi = __shfl_xor(gi, off);
      if (om > gm || (om == gm && oi < gi)) { gm = om; gi = oi; }
    }
    float term = 0.0f;
#pragma unroll
    for (int j = 0; j < 8; ++j) term += sv[j] * __expf(mv[j] - gm);
#pragma unroll
    for (int off = 1; off < 64; off <<= 1) term += __shfl_xor(term, off);
    if (lane == 0) {
      toks[wv] = gi;
      if (jt == 0) {
        scores[row] -= logf(term);      // += max - logsumexp
        tok_seq[step * BB + row] = gi;  // seq column `step`
      }
    }
  }
  __syncthreads();
  if (step == TSTEPS) return;

  for (int i = tid; i < 4 * EE; i += 256) {
    const int r = i >> 8, c = i & (EE - 1);
    const float e = emb[(size_t)toks[r] * EE + c];
    xs[r][c] = e > 0.0f ? e : 0.0f;
  }
  for (int i = tid; i < 4 * HH; i += 256) {
    const int r = i >> 9, c = i & (HH - 1);
    hsm[r][c] = hin[(r0 + r) * HH + c];
  }
  __syncthreads();

  const int jh = tid & 31, kq = tid >> 5;  // 32 cols x 8 k-slices
  const int j = j0 + jh;
  float ai[3][4], ah[3][4];
#pragma unroll
  for (int g = 0; g < 3; ++g)
#pragma unroll
    for (int r = 0; r < 4; ++r) { ai[g][r] = 0.0f; ah[g][r] = 0.0f; }

#pragma unroll 2
  for (int q = 0; q < 8; ++q) {
    const int k4 = kq * 32 + q * 4;
    float4 xr[4];
#pragma unroll
    for (int r = 0; r < 4; ++r) xr[r] = *(const float4*)&xs[r][k4];
#pragma unroll
    for (int g = 0; g < 3; ++g) {
      const float4 w = *(const float4*)&W_ih[(size_t)(g * HH + j) * EE + k4];
#pragma unroll
      for (int r = 0; r < 4; ++r) {
        ai[g][r] = fmaf(xr[r].x, w.x, ai[g][r]);
        ai[g][r] = fmaf(xr[r].y, w.y, ai[g][r]);
        ai[g][r] = fmaf(xr[r].z, w.z, ai[g][r]);
        ai[g][r] = fmaf(xr[r].w, w.w, ai[g][r]);
      }
    }
  }
#pragma unroll 2
  for (int q = 0; q < 16; ++q) {
    const int k4 = kq * 64 + q * 4;
    float4 hr[4];
#pragma unroll
    for (int r = 0; r < 4; ++r) hr[r] = *(const float4*)&hsm[r][k4];
#pragma unroll
    for (int g = 0; g < 3; ++g) {
      const float4 w = *(const float4*)&W_hh[(size_t)(g * HH + j) * HH + k4];
#pragma unroll
      for (int r = 0; r < 4; ++r) {
        ah[g][r] = fmaf(hr[r].x, w.x, ah[g][r]);
        ah[g][r] = fmaf(hr[r].y, w.y, ah[g][r]);
        ah[g][r] = fmaf(hr[r].z, w.z, ah[g][r]);
        ah[g][r] = fmaf(hr[r].w, w.w, ah[g][r]);
      }
    }
  }
  {
    const int base = kq * 34 + jh;
#pragma unroll
    for (int g = 0; g < 3; ++g)
#pragma unroll
      for (int r = 0; r < 4; ++r) {
        gpart[(g * 4 + r) * 272 + base] = ai[g][r];
        gpart[(12 + g * 4 + r) * 272 + base] = ah[g][r];
      }
  }
  __syncthreads();

  if (tid < 128) {
    const int r = tid >> 5, jh2 = tid & 31;
    const int j2 = j0 + jh2;
    float g6[6];
#pragma unroll
    for (int c = 0; c < 6; ++c) {
      const int cc = (c < 3) ? (c * 4 + r) : (12 + (c - 3) * 4 + r);
      float s = 0.0f;
#pragma unroll
      for (int q = 0; q < 8; ++q) s += gpart[cc * 272 + q * 34 + jh2];
      g6[c] = s;
    }
    const float ir = g6[0] + b_ih[j2];
    const float iz = g6[1] + b_ih[HH + j2];
    const float in_ = g6[2] + b_ih[2 * HH + j2];
    const float hr_ = g6[3] + b_hh[j2];
    const float hz = g6[4] + b_hh[HH + j2];
    const float hn = g6[5] + b_hh[2 * HH + j2];
    const float rr = 1.0f / (1.0f + expf(-(ir + hr_)));
    const float zz = 1.0f / (1.0f + expf(-(iz + hz)));
    const float nn = tanhf(in_ + rr * hn);
    st_agent(&hout[(r0 + r) * HH + j2], (1.0f - zz) * nn + zz * hsm[r][j2]);
  }
}

// ---------------------------------------------------------------------------
// Persistent kernel, REGISTER-RESIDENT Wt + producer-flag sync.
// Occupancy pinned at exactly 2 waves/EU (= 2 blocks/CU at 256 thr):
// allocator budget 256 VGPRs so wreg(128) + working set stays in registers.
// 512 blocks x 256 thr. hslot[t] (slot t): 128 GRU producers, groups of 16.
// sslot[t] (slot 32+t): 500 gemv producers, groups of 64 (last 52).
// ---------------------------------------------------------------------------
__global__ __attribute__((amdgpu_flat_work_group_size(256, 256),
                          amdgpu_waves_per_eu(2, 2))) void k_persist(
    const float* __restrict__ Wt, const float* __restrict__ emb,
    const float* __restrict__ W_ih, const float* __restrict__ W_hh,
    const float* __restrict__ b_ih, const float* __restrict__ b_hh,
    const float* __restrict__ bout,
    float* hseq, float* pmT, float* psT, int* pidxT,
    float* scores, int* tok_seq, unsigned* sync) {
  __shared__ __align__(16) float smem[SMEM_FLOATS];
  __shared__ int toks[4];
  const int bid = blockIdx.x, tid = threadIdx.x;
  const int c2 = tid & 31, kq = tid >> 5;  // 2 cols, 64-k slice
  const int vb = bid;                      // live if < NCH

  // ---- prologue: pin Wt slice in registers (once) ----
  float2 wreg[64];
  if (vb < NCH) {
    const float* wp = Wt + (size_t)(kq * 64) * VV + vb * 64 + c2 * 2;
#pragma unroll
    for (int k = 0; k < 64; ++k)
      wreg[k] = *(const float2*)(wp + (size_t)k * VV);
  } else {
#pragma unroll
    for (int k = 0; k < 64; ++k) wreg[k] = make_float2(0.0f, 0.0f);
  }

  float* hs = smem;              // [32][512]
  float* part = smem + 16384;    // [4][8][64]

  for (int t = 0; t <= TSTEPS; ++t) {
    const float* hin = hseq + (size_t)t * HB;
    float* hout = hseq + (size_t)(t + 1) * HB;
    const int tp = (t > 0) ? (t - 1) : 0;

    // ---- phase A: select + GRU (select-only at t==TSTEPS) ----
    if (bid < 128) {
      if (t > 0) sync_wait(sync + (size_t)(32 + tp) * SLOT_U, bid & 7);
      gru_body(bid, tid, t, smem, toks, emb, W_ih, W_hh, b_ih, b_hh,
               hin, hout, pmT + (size_t)tp * SB, psT + (size_t)tp * SB,
               pidxT + (size_t)tp * SB, scores, tok_seq);
      if (t < TSTEPS)
        sync_arrive(sync + (size_t)t * SLOT_U, bid >> 4, 16u);
    }
    if (t == TSTEPS) break;

    // ---- phase B: register-resident gemv + chunk stats ----
    if (vb < NCH) {
      sync_wait(sync + (size_t)t * SLOT_U, bid & 7);
      float* pm = pmT + (size_t)t * SB;
      float* ps = psT + (size_t)t * SB;
      int* pidx = pidxT + (size_t)t * SB;
      // stage h (32x512)
      {
        float4* hd = (float4*)hs;
        const float4* hp = (const float4*)hout;
#pragma unroll
        for (int i = 0; i < 16; ++i) hd[i * 256 + tid] = hp[i * 256 + tid];
      }
      __syncthreads();

      const int w = tid >> 6;        // wave id 0..3
      const int rr = tid >> 5;       // reduce-stage row 0..7
      const int cp = tid & 31;       // reduce-stage col-pair
#pragma unroll 1
      for (int rc = 0; rc < 4; ++rc) {
        float acc0[8], acc1[8];
#pragma unroll
        for (int r = 0; r < 8; ++r) { acc0[r] = 0.0f; acc1[r] = 0.0f; }
#pragma unroll
        for (int r = 0; r < 8; ++r) {
          const float* hrow = hs + (rc * 8 + r) * 512 + kq * 64;
#pragma unroll
          for (int j = 0; j < 16; ++j) {
            const float4 h4 = *(const float4*)(hrow + j * 4);
            acc0[r] = fmaf(h4.x, wreg[j * 4 + 0].x, acc0[r]);
            acc1[r] = fmaf(h4.x, wreg[j * 4 + 0].y, acc1[r]);
            acc0[r] = fmaf(h4.y, wreg[j * 4 + 1].x, acc0[r]);
            acc1[r] = fmaf(h4.y, wreg[j * 4 + 1].y, acc1[r]);
            acc0[r] = fmaf(h4.z, wreg[j * 4 + 2].x, acc0[r]);
            acc1[r] = fmaf(h4.z, wreg[j * 4 + 2].y, acc1[r]);
            acc0[r] = fmaf(h4.w, wreg[j * 4 + 3].x, acc0[r]);
            acc1[r] = fmaf(h4.w, wreg[j * 4 + 3].y, acc1[r]);
          }
        }
        // merge kq pairs within wave (bit5)
#pragma unroll
        for (int r = 0; r < 8; ++r) {
          acc0[r] += __shfl_xor(acc0[r], 32);
          acc1[r] += __shfl_xor(acc1[r], 32);
        }
        if ((tid & 32) == 0) {   // lanes with even kq hold the pair sum
#pragma unroll
          for (int r = 0; r < 8; ++r) {
            float2* pp = (float2*)&part[w * 512 + r * 64 + c2 * 2];
            *pp = make_float2(acc0[r], acc1[r]);
          }
        }
        __syncthreads();
        // 4-way reduce + bias + per-row stats over 32 lanes
        {
          float l0 = 0.0f, l1 = 0.0f;
#pragma unroll
          for (int ww = 0; ww < 4; ++ww) {
            const float2 p = *(const float2*)&part[ww * 512 + rr * 64 + cp * 2];
            l0 += p.x; l1 += p.y;
          }
          const float2 bb = *(const float2*)(bout + vb * 64 + cp * 2);
          l0 += bb.x; l1 += bb.y;
          const int col0 = vb * 64 + cp * 2;
          float m = l0; int ii = col0;
          if (l1 > m) { m = l1; ii = col0 + 1; }
#pragma unroll
          for (int off = 1; off < 32; off <<= 1) {
            const float om = __shfl_xor(m, off);
            const int oi = __shfl_xor(ii, off);
            if (om > m || (om == m && oi < ii)) { m = om; ii = oi; }
          }
          float e = __expf(l0 - m) + __expf(l1 - m);
#pragma unroll
          for (int off = 1; off < 32; off <<= 1) e += __shfl_xor(e, off);
          if (cp == 0) {
            const int grow = rc * 8 + rr;
            st_agent(&pm[grow * PSTR + vb], m);
            st_agent(&ps[grow * PSTR + vb], e);
            st_agent_i(&pidx[grow * PSTR + vb], ii);
          }
        }
        __syncthreads();  // part reused next chunk
      }
      sync_arrive(sync + (size_t)(32 + t) * SLOT_U, bid >> 6,
                  (bid >> 6) < 7 ? 64u : 52u);
    }
  }
}

// ---------------------------------------------------------------------------
// Fallback standalone kernels (R9 path) — global-load bodies.
// ---------------------------------------------------------------------------
__global__ __launch_bounds__(256) void k_gemv_fused(
    const float* __restrict__ Wt, const float* __restrict__ hmat,
    const float* __restrict__ bout,
    float* __restrict__ pm, float* __restrict__ ps, int* __restrict__ pidx) {
  __shared__ __align__(16) float smem[16512];
  gemv_body_glb(blockIdx.x, threadIdx.x, smem, Wt, hmat, bout, pm, ps, pidx);
}

__global__ __launch_bounds__(256) void k_gru(
    const int step, const float* __restrict__ emb,
    const float* __restrict__ W_ih, const float* __restrict__ W_hh,
    const float* __restrict__ b_ih, const float* __restrict__ b_hh,
    const float* __restrict__ hin, float* __restrict__ hout,
    const float* __restrict__ pmt, const float* __restrict__ pst,
    const int* __restrict__ pidxt,
    float* __restrict__ scores, int* __restrict__ tok_seq) {
  __shared__ __align__(16) float smem[9600];
  __shared__ int toks[4];
  gru_body(blockIdx.x, threadIdx.x, step, smem, toks, emb, W_ih, W_hh,
           b_ih, b_hh, hin, hout, pmt, pst, pidxt, scores, tok_seq);
}

// ---------------------------------------------------------------------------
// Full-output writer: one-hot rows composed inline (no memset), h x3,
// scores x3. All stores float4, coalesced.
// ---------------------------------------------------------------------------
__global__ __launch_bounds__(256) void k_out(
    const int* __restrict__ tok_seq, const float* __restrict__ hfin,
    const float* __restrict__ scores, float* __restrict__ out) {
  const int blk = blockIdx.x, tid = threadIdx.x;
  if (blk < BB * (TSTEPS + 1)) {           // one (b,t) one-hot row
    const int b = blk / (TSTEPS + 1), t = blk % (TSTEPS + 1);
    const int tok = tok_seq[t * BB + b];
    const int tq = tok >> 2, tl = tok & 3;
    float4* op = (float4*)(out + (size_t)blk * VV);
    for (int i = tid; i < VV / 4; i += 256) {
      float4 z = {0.0f, 0.0f, 0.0f, 0.0f};
      if (i == tq) (&z.x)[tl] = 1.0f;
      op[i] = z;
    }
  } else if (blk < BB * (TSTEPS + 1) + 12) {  // h x3: 12288 float4
#pragma unroll
    for (int it = 0; it < 4; ++it) {
      const int idx = (blk - BB * (TSTEPS + 1)) * 1024 + it * 256 + tid;
      if (idx < H_ELEMS / 4) {
        const int fi = idx * 4;
        const int b = fi / (3 * HH);
        const int j0 = (fi % (3 * HH)) % HH;
        ((float4*)(out + DEC_ELEMS))[idx] =
            *(const float4*)(hfin + b * HH + j0);
      }
    }
  } else {                                   // scores x3: 96 floats
    if (tid < BB * 3) {
      out[(size_t)DEC_ELEMS + H_ELEMS + tid] = scores[tid / 3];
    }
  }
}

// ---------------------------------------------------------------------------
extern "C" void kernel_launch(void* const* d_in, const int* in_sizes, int n_in,
                              void* d_out, int out_size, void* d_ws, size_t ws_size,
                              hipStream_t stream) {
  const float* enc_h = (const float*)d_in[1];
  const float* emb   = (const float*)d_in[2];
  const float* W_ih  = (const float*)d_in[3];
  const float* W_hh  = (const float*)d_in[4];
  const float* b_ih  = (const float*)d_in[5];
  const float* b_hh  = (const float*)d_in[6];
  const float* W_out = (const float*)d_in[7];
  const float* b_out = (const float*)d_in[8];
  float* out = (float*)d_out;

  // workspace layout (floats) — ~74.5 MB total
  float* ws = (float*)d_ws;
  float* Wt_out  = ws;                        // 16,384,000
  float* hseq    = Wt_out + 16384000;         // 34 * 16384 (h after t steps)
  float* pmT     = hseq + 34 * HB;            // 32 * 16384 (per-step stats)
  float* psT     = pmT + 32 * SB;             // 32 * 16384
  float* scores  = psT + 32 * SB;             // 32
  int*   pidxT   = (int*)(scores + BB);       // 32 * 16384
  int*   tok_seq = pidxT + 32 * SB;           // 33*32
  unsigned* sync = (unsigned*)(tok_seq + BB * (TSTEPS + 1));  // 64*1024

  k_transpose_out<<<dim3(1000, 16), 256, 0, stream>>>(W_out, Wt_out);
  k_init<<<64, 256, 0, stream>>>(enc_h, hseq, scores, tok_seq, sync);

  // ---- persistent register-resident path (coop launch for co-residency) ----
  const float* Wt_c = Wt_out;
  void* args[] = {(void*)&Wt_c,  (void*)&emb,  (void*)&W_ih, (void*)&W_hh,
                  (void*)&b_ih,  (void*)&b_hh, (void*)&b_out,
                  (void*)&hseq,  (void*)&pmT,  (void*)&psT,  (void*)&pidxT,
                  (void*)&scores, (void*)&tok_seq, (void*)&sync};
  hipError_t ce = hipLaunchCooperativeKernel(
      reinterpret_cast<const void*>(&k_persist), dim3(512), dim3(256),
      args, 0u, stream);

  if (ce != hipSuccess) {
    // ---- fallback: multi-kernel path (global-load bodies) ----
    for (int t = 0; t < TSTEPS; ++t) {
      const int tp = (t > 0) ? (t - 1) : 0;
      k_gru<<<128, 256, 0, stream>>>(
          t, emb, W_ih, W_hh, b_ih, b_hh,
          hseq + (size_t)t * HB, hseq + (size_t)(t + 1) * HB,
          pmT + (size_t)tp * SB, psT + (size_t)tp * SB,
          pidxT + (size_t)tp * SB, scores, tok_seq);
      k_gemv_fused<<<NCH, 256, 0, stream>>>(
          Wt_out, hseq + (size_t)(t + 1) * HB, b_out,
          pmT + (size_t)t * SB, psT + (size_t)t * SB,
          pidxT + (size_t)t * SB);
    }
    k_gru<<<128, 256, 0, stream>>>(
        TSTEPS, emb, W_ih, W_hh, b_ih, b_hh,
        hseq + (size_t)TSTEPS * HB, hseq + (size_t)(TSTEPS + 1) * HB,
        pmT + (size_t)(TSTEPS - 1) * SB, psT + (size_t)(TSTEPS - 1) * SB,
        pidxT + (size_t)(TSTEPS - 1) * SB, scores, tok_seq);
  }

  // final h = hseq[32]; full-output writer
  k_out<<<BB * (TSTEPS + 1) + 13, 256, 0, stream>>>(
      tok_seq, hseq + (size_t)TSTEPS * HB, scores, out);
}